// Round 2
// baseline (1693.292 us; speedup 1.0000x reference)
//
#include <hip/hip_runtime.h>

// ---------------------------------------------------------------------------
// QRNN (window=1, fo-pool) on MI355X — CHUNKED pipeline (fits small d_ws).
// Per s-chunk (CH rows of S, all B batches):
//   [gemm1c] x@W1+b1 -> act (fp32 vector, K=64) -> g1 bf16 [B][CH][1536]
//   [scan1c] fo-pool layer1 over chunk, carry c1[B][H]; h1c = sig(o)*c
//   [gemm2c] h1c@W2+b2 -> act (bf16 MFMA 16x16x32) -> g2 (o-plane only s=1023)
//   [scan2c] fo-pool layer2 over chunk, carry c2[B][H]; last chunk -> h2l
// Then final_fc: h2l @ Wfc + bfc.
// ws peak: CH=128 -> 119,799,808 B;  CH=32 fallback -> 31,719,424 B.
// ---------------------------------------------------------------------------

using u16 = unsigned short;
using u32 = unsigned int;

typedef __attribute__((ext_vector_type(8))) short bf16x8;
typedef __attribute__((ext_vector_type(4))) float f32x4;

#define B_  128
#define S_  1024
#define D_  64
#define H_  512
#define N3_ 1536

__device__ __forceinline__ u16 f2bf(float f) {        // RNE float->bf16
  u32 u = __builtin_bit_cast(u32, f);
  u = (u + 0x7fffu + ((u >> 16) & 1u)) >> 16;
  return (u16)u;
}
__device__ __forceinline__ float bf2f(u16 h) {
  u32 u = ((u32)h) << 16;
  return __builtin_bit_cast(float, u);
}
__device__ __forceinline__ float sigm(float x) {      // plain div: no exotic builtins
  return 1.f / (1.f + __expf(-x));
}
__device__ __forceinline__ float tanh_(float x) {
  float t = __expf(2.f * x);                          // inf-safe: (inf-1)/(inf+1)->nan? no:
  return (t - 1.f) / (t + 1.f);                       // t=inf -> inf/inf = nan! guard:
}
__device__ __forceinline__ float tanh_safe(float x) {
  float ax = fabsf(x);
  float t = __expf(-2.f * ax);                        // in (0,1]
  float r = (1.f - t) / (1.f + t);                    // tanh(|x|), always finite
  return copysignf(r, x);
}

// ---------------------------------------------------------------------------
// k0: W2 (512,1536) f32 -> w2t (1536,512) bf16   (tiny one-off)
// ---------------------------------------------------------------------------
__global__ __launch_bounds__(256) void k0_w2t(const float* __restrict__ W2,
                                              u16* __restrict__ w2t) {
  __shared__ u16 tile[64][65];
  const int n0 = blockIdx.x * 64, k0 = blockIdx.y * 64;
  const int t = threadIdx.x;
  const int c = t & 63, r0 = t >> 6;
#pragma unroll
  for (int i = 0; i < 16; i++) {
    int r = r0 + i * 4;
    tile[r][c] = f2bf(W2[(size_t)(k0 + r) * N3_ + n0 + c]);
  }
  __syncthreads();
#pragma unroll
  for (int i = 0; i < 16; i++) {
    int cc = r0 + i * 4;
    w2t[(size_t)(n0 + cc) * H_ + k0 + c] = tile[c][cc];
  }
}

// ---------------------------------------------------------------------------
// gemm1c<CH>: fp32 GEMM + act for one s-chunk. M = B*CH rows (row r ->
// x[b= r/CH][s0 + r%CH][:]). Tile 128x128, 256 thr, 8x8 micro-tile.
// g1 cols [0,512)=tanh(z), [512,1536)=sigmoid(f,o), post-activation bf16.
// ---------------------------------------------------------------------------
template <int CH>
__global__ __launch_bounds__(256) void gemm1c(const float* __restrict__ x,
                                              const float* __restrict__ W1,
                                              const float* __restrict__ b1,
                                              u16* __restrict__ g1, int s0) {
  __shared__ float xs[128][68];
  __shared__ float wsh[64][128];
  const int t = threadIdx.x;
  const int m0 = blockIdx.y * 128;
  const int n0 = blockIdx.x * 128;

#pragma unroll
  for (int i = 0; i < 8; i++) {               // stage x tile 128x64
    int idx = t + i * 256;
    int row = idx >> 4, c4 = idx & 15;
    int r = m0 + row;
    size_t xrow = (size_t)(r / CH) * S_ + s0 + (r % CH);
    float4 v = *(const float4*)(x + xrow * D_ + c4 * 4);
    *(float4*)(&xs[row][c4 * 4]) = v;
  }
#pragma unroll
  for (int i = 0; i < 8; i++) {               // stage W1 tile 64x128
    int idx = t + i * 256;
    int row = idx >> 5, c4 = idx & 31;
    float4 v = *(const float4*)(W1 + (size_t)row * N3_ + n0 + c4 * 4);
    *(float4*)(&wsh[row][c4 * 4]) = v;
  }
  __syncthreads();

  const int rt = t >> 4, ct = t & 15;
  float acc[8][8];
#pragma unroll
  for (int i = 0; i < 8; i++)
#pragma unroll
    for (int j = 0; j < 8; j++) acc[i][j] = 0.f;

#pragma unroll 4
  for (int k = 0; k < 64; k++) {
    float4 q0 = *(const float4*)(&wsh[k][ct * 8]);
    float4 q1 = *(const float4*)(&wsh[k][ct * 8 + 4]);
    float bq[8] = {q0.x, q0.y, q0.z, q0.w, q1.x, q1.y, q1.z, q1.w};
#pragma unroll
    for (int i = 0; i < 8; i++) {
      float av = xs[rt + 16 * i][k];
#pragma unroll
      for (int j = 0; j < 8; j++) acc[i][j] = fmaf(av, bq[j], acc[i][j]);
    }
  }

  const bool isz = (n0 < 512);
  float bvals[8];
#pragma unroll
  for (int j = 0; j < 8; j++) bvals[j] = b1[n0 + ct * 8 + j];
#pragma unroll
  for (int i = 0; i < 8; i++) {
    const int m = m0 + rt + 16 * i;
    u32 w[4];
#pragma unroll
    for (int jj = 0; jj < 4; jj++) {
      float g0 = acc[i][2 * jj] + bvals[2 * jj];
      float g1v = acc[i][2 * jj + 1] + bvals[2 * jj + 1];
      float v0 = isz ? tanh_safe(g0) : sigm(g0);
      float v1 = isz ? tanh_safe(g1v) : sigm(g1v);
      w[jj] = (u32)f2bf(v0) | ((u32)f2bf(v1) << 16);
    }
    uint4 sv; sv.x = w[0]; sv.y = w[1]; sv.z = w[2]; sv.w = w[3];
    *(uint4*)(g1 + (size_t)m * N3_ + n0 + ct * 8) = sv;
  }
}

// ---------------------------------------------------------------------------
// scan1c<CH>: fo-pool layer1 over one chunk. thread=(b,h). h1c = o*c.
// ---------------------------------------------------------------------------
template <int CH>
__global__ __launch_bounds__(256) void scan1c(const u16* __restrict__ g1,
                                              u16* __restrict__ h1c,
                                              float* __restrict__ c1, int first) {
  const int tid = blockIdx.x * 256 + threadIdx.x;
  const int b = tid >> 9, h = tid & 511;
  const u16* A = g1 + (size_t)b * CH * N3_ + h;
  u16* O = h1c + (size_t)b * CH * H_ + h;
  float c = first ? 0.f : c1[tid];
#pragma unroll 8
  for (int ds = 0; ds < CH; ds++) {
    const u16* p = A + (size_t)ds * N3_;
    float za = bf2f(p[0]);
    float fa = bf2f(p[512]);
    float oa = bf2f(p[1024]);
    c = fmaf(fa, c - za, za);          // f*c + (1-f)*z
    O[(size_t)ds * H_] = f2bf(oa * c);
  }
  c1[tid] = c;
}

// ---------------------------------------------------------------------------
// gemm2c<CH>: bf16 MFMA GEMM + act for one chunk. M=B*CH, K=512, N=1536.
// Tile 128x128, BK=32, 4 waves (2x2), 4x4 fragments each. XOR-swizzled LDS.
// o-plane (n>=1024) written only where global s == S-1.
// ---------------------------------------------------------------------------
__device__ __forceinline__ int swz_off(int row, int seg) {  // byte offset, 64B rows
  return row * 64 + (((seg ^ (row & 3) ^ ((row >> 2) & 3)) & 3) << 4);
}

template <int CH>
__global__ __launch_bounds__(256) void gemm2c(const u16* __restrict__ h1c,
                                              const u16* __restrict__ w2t,
                                              const float* __restrict__ b2,
                                              u16* __restrict__ g2, int s0) {
  __shared__ u16 As[128 * 32];
  __shared__ u16 Bs[128 * 32];
  const int t = threadIdx.x;
  const int l = t & 63, wv = t >> 6;
  const int wm = wv >> 1, wn = wv & 1;
  const int lr = l & 15, lg = l >> 4;
  const int m0 = blockIdx.y * 128, n0 = blockIdx.x * 128;

  int wo[2]; size_t ga[2], gb[2];
#pragma unroll
  for (int i = 0; i < 2; i++) {
    int idx = t + i * 256;               // 0..511
    int row = idx >> 2, seg = idx & 3;   // 128 rows x 4 segs of 8 bf16
    wo[i] = swz_off(row, seg);
    ga[i] = (size_t)(m0 + row) * H_ + seg * 8;
    gb[i] = (size_t)(n0 + row) * H_ + seg * 8;
  }
  int aoff[4], boff[4];
#pragma unroll
  for (int i = 0; i < 4; i++) {
    aoff[i] = swz_off(wm * 64 + i * 16 + lr, lg);
    boff[i] = swz_off(wn * 64 + i * 16 + lr, lg);
  }

  const f32x4 zero4 = {0.f, 0.f, 0.f, 0.f};
  f32x4 acc[4][4];
#pragma unroll
  for (int i = 0; i < 4; i++)
#pragma unroll
    for (int j = 0; j < 4; j++) acc[i][j] = zero4;

  uint4 av[2], bv[2];
#pragma unroll
  for (int i = 0; i < 2; i++) {
    av[i] = *(const uint4*)(h1c + ga[i]);
    bv[i] = *(const uint4*)(w2t + gb[i]);
  }

  for (int kt = 0; kt < 16; kt++) {
    __syncthreads();
#pragma unroll
    for (int i = 0; i < 2; i++) {
      *(uint4*)((char*)As + wo[i]) = av[i];
      *(uint4*)((char*)Bs + wo[i]) = bv[i];
    }
    if (kt < 15) {
      const int ko = (kt + 1) * 32;
#pragma unroll
      for (int i = 0; i < 2; i++) {
        av[i] = *(const uint4*)(h1c + ga[i] + ko);
        bv[i] = *(const uint4*)(w2t + gb[i] + ko);
      }
    }
    __syncthreads();
    bf16x8 af[4], bfr[4];
#pragma unroll
    for (int i = 0; i < 4; i++) af[i] = *(const bf16x8*)((const char*)As + aoff[i]);
#pragma unroll
    for (int j = 0; j < 4; j++) bfr[j] = *(const bf16x8*)((const char*)Bs + boff[j]);
#pragma unroll
    for (int i = 0; i < 4; i++) {
#pragma unroll
      for (int j = 0; j < 4; j++) {
        acc[i][j] = __builtin_amdgcn_mfma_f32_16x16x32_bf16(af[i], bfr[j], acc[i][j], 0, 0, 0);
      }
    }
  }

  // epilogue: C/D layout col=lane&15, row=(lane>>4)*4+reg  [m89-verified]
  const bool isz = (n0 < 512);
  const bool iso = (n0 >= 1024);
  float bvv[4];
#pragma unroll
  for (int j = 0; j < 4; j++) bvv[j] = b2[n0 + wn * 64 + j * 16 + lr];
#pragma unroll
  for (int i = 0; i < 4; i++) {
#pragma unroll
    for (int r = 0; r < 4; r++) {
      const int m = m0 + wm * 64 + i * 16 + lg * 4 + r;
      const int ds = m & (CH - 1);
      const bool wr = !iso || (s0 + ds == S_ - 1);   // o only at global s=1023
#pragma unroll
      for (int j = 0; j < 4; j++) {
        const int n = n0 + wn * 64 + j * 16 + lr;
        float g = acc[i][j][r] + bvv[j];
        float v = isz ? tanh_safe(g) : sigm(g);
        if (wr) g2[(size_t)m * N3_ + n] = f2bf(v);
      }
    }
  }
}

// ---------------------------------------------------------------------------
// scan2c<CH>: fo-pool layer2 over one chunk; carry c2. Last chunk -> h2l.
// ---------------------------------------------------------------------------
template <int CH>
__global__ __launch_bounds__(256) void scan2c(const u16* __restrict__ g2,
                                              float* __restrict__ c2,
                                              float* __restrict__ h2l,
                                              int first, int last) {
  const int tid = blockIdx.x * 256 + threadIdx.x;
  const int b = tid >> 9, h = tid & 511;
  const u16* A = g2 + (size_t)b * CH * N3_ + h;
  float c = first ? 0.f : c2[tid];
#pragma unroll 8
  for (int ds = 0; ds < CH; ds++) {
    const u16* p = A + (size_t)ds * N3_;
    float za = bf2f(p[0]);
    float fa = bf2f(p[512]);
    c = fmaf(fa, c - za, za);
  }
  c2[tid] = c;
  if (last) {
    float oa = bf2f(A[(size_t)(CH - 1) * N3_ + 1024]);
    h2l[tid] = oa * c;
  }
}

// ---------------------------------------------------------------------------
// final_fc: out = h2_last @ Wfc + bfc.  (128x512)@(512x64) fp32.
// ---------------------------------------------------------------------------
__global__ __launch_bounds__(256) void final_fc(const float* __restrict__ h2l,
                                                const float* __restrict__ Wfc,
                                                const float* __restrict__ bfc,
                                                float* __restrict__ out) {
  __shared__ float red[4][64];
  const int b = blockIdx.x;
  const int t = threadIdx.x, d = t & 63, q = t >> 6;
  const float* hrow = h2l + (size_t)b * H_;
  float acc = 0.f;
#pragma unroll 4
  for (int h = q * 128; h < (q + 1) * 128; h++)
    acc = fmaf(hrow[h], Wfc[(size_t)h * D_ + d], acc);
  red[q][d] = acc;
  __syncthreads();
  if (q == 0)
    out[(size_t)b * D_ + d] = red[0][d] + red[1][d] + red[2][d] + red[3][d] + bfc[d];
}

// ---------------------------------------------------------------------------
template <int CH>
static void run_pipeline(const float* x, const float* W1, const float* b1,
                         const float* W2, const float* b2,
                         const float* Wfc, const float* bfc,
                         float* out, char* ws, hipStream_t stream) {
  constexpr size_t G1B  = (size_t)B_ * CH * N3_ * 2;   // g1 bytes
  constexpr size_t H1B  = (size_t)B_ * CH * H_ * 2;    // h1c bytes
  constexpr size_t W2TB = (size_t)N3_ * H_ * 2;        // 1,572,864
  u16*   g1  = (u16*)(ws);
  u16*   h1c = (u16*)(ws + G1B);
  u16*   g2  = (u16*)(ws + G1B + H1B);
  u16*   w2t = (u16*)(ws + G1B + H1B + G1B);
  float* c1  = (float*)(ws + G1B + H1B + G1B + W2TB);
  float* c2  = c1 + B_ * H_;
  float* h2l = c2 + B_ * H_;

  k0_w2t<<<dim3(N3_ / 64, H_ / 64), 256, 0, stream>>>(W2, w2t);
  constexpr int NC = S_ / CH;
  for (int i = 0; i < NC; i++) {
    const int s0 = i * CH;
    gemm1c<CH><<<dim3(N3_ / 128, (B_ * CH) / 128), 256, 0, stream>>>(x, W1, b1, g1, s0);
    scan1c<CH><<<(B_ * H_) / 256, 256, 0, stream>>>(g1, h1c, c1, i == 0);
    gemm2c<CH><<<dim3(N3_ / 128, (B_ * CH) / 128), 256, 0, stream>>>(h1c, w2t, b2, g2, s0);
    scan2c<CH><<<(B_ * H_) / 256, 256, 0, stream>>>(g2, c2, h2l, i == 0, i == NC - 1);
  }
  final_fc<<<B_, 256, 0, stream>>>(h2l, Wfc, bfc, out);
}

extern "C" void kernel_launch(void* const* d_in, const int* in_sizes, int n_in,
                              void* d_out, int out_size, void* d_ws, size_t ws_size,
                              hipStream_t stream) {
  (void)in_sizes; (void)n_in; (void)out_size;
  const float* x   = (const float*)d_in[0];
  const float* W1  = (const float*)d_in[1];
  const float* b1  = (const float*)d_in[2];
  const float* W2  = (const float*)d_in[3];
  const float* b2  = (const float*)d_in[4];
  const float* Wfc = (const float*)d_in[5];
  const float* bfc = (const float*)d_in[6];
  float* out = (float*)d_out;
  char* ws = (char*)d_ws;

  // peak ws need: CH=128 -> 119,799,808 B ; CH=32 -> 31,719,424 B
  if (ws_size >= 119799808ull)
    run_pipeline<128>(x, W1, b1, W2, b2, Wfc, bfc, out, ws, stream);
  else
    run_pipeline<32>(x, W1, b1, W2, b2, Wfc, bfc, out, ws, stream);
}

// Round 3
// 1017.415 us; speedup vs baseline: 1.6643x; 1.6643x over previous
//
#include <hip/hip_runtime.h>

// ---------------------------------------------------------------------------
// QRNN (window=1, fo-pool) on MI355X — chunked pipeline, round 2.
// gemm2c: N=1024 only (z,f); o-plane computed for the 128 s=1023 rows by
// o_last_k. gemm2c uses global_load_lds dbuf (linear LDS dest, pre-swizzled
// global src), XOR-swizzled ds_read_b128, LDS-transposed epilogue (16B
// stores, full cache lines), XCD-aware block swizzle.
// ws peak: CH=128 -> 103,284,736 B ; CH=32 -> 27,787,264 B.
// ---------------------------------------------------------------------------

using u16 = unsigned short;
using u32 = unsigned int;

typedef __attribute__((ext_vector_type(8))) short bf16x8;
typedef __attribute__((ext_vector_type(4))) float f32x4;

#define B_  128
#define S_  1024
#define D_  64
#define H_  512
#define N3_ 1536
#define N2_ 1024   // gemm2 output cols (z,f only)

__device__ __forceinline__ u16 f2bf(float f) {        // RNE float->bf16
  u32 u = __builtin_bit_cast(u32, f);
  u = (u + 0x7fffu + ((u >> 16) & 1u)) >> 16;
  return (u16)u;
}
__device__ __forceinline__ float bf2f(u16 h) {
  u32 u = ((u32)h) << 16;
  return __builtin_bit_cast(float, u);
}
__device__ __forceinline__ float sigm(float x) {
  return 1.f / (1.f + __expf(-x));
}
__device__ __forceinline__ float tanh_safe(float x) {
  float ax = fabsf(x);
  float t = __expf(-2.f * ax);                        // in (0,1]
  float r = (1.f - t) / (1.f + t);                    // always finite
  return copysignf(r, x);
}
__device__ __forceinline__ int swz_off(int row, int seg) {  // byte off, 64B rows
  return row * 64 + (((seg ^ (row & 3) ^ ((row >> 2) & 3)) & 3) << 4);
}

// ---------------------------------------------------------------------------
// k0: W2 (512,1536) f32 -> w2t (1536,512) bf16   (tiny one-off)
// ---------------------------------------------------------------------------
__global__ __launch_bounds__(256) void k0_w2t(const float* __restrict__ W2,
                                              u16* __restrict__ w2t) {
  __shared__ u16 tile[64][65];
  const int n0 = blockIdx.x * 64, k0 = blockIdx.y * 64;
  const int t = threadIdx.x;
  const int c = t & 63, r0 = t >> 6;
#pragma unroll
  for (int i = 0; i < 16; i++) {
    int r = r0 + i * 4;
    tile[r][c] = f2bf(W2[(size_t)(k0 + r) * N3_ + n0 + c]);
  }
  __syncthreads();
#pragma unroll
  for (int i = 0; i < 16; i++) {
    int cc = r0 + i * 4;
    w2t[(size_t)(n0 + cc) * H_ + k0 + c] = tile[c][cc];
  }
}

// ---------------------------------------------------------------------------
// gemm1c<CH>: fp32 GEMM + act for one s-chunk. Tile 128x128, 8x8 micro-tile.
// ---------------------------------------------------------------------------
template <int CH>
__global__ __launch_bounds__(256) void gemm1c(const float* __restrict__ x,
                                              const float* __restrict__ W1,
                                              const float* __restrict__ b1,
                                              u16* __restrict__ g1, int s0) {
  __shared__ float xs[128][68];
  __shared__ float wsh[64][128];
  const int t = threadIdx.x;

  int bx, by;                                   // XCD-aware swizzle (bijective)
  { constexpr int GY = (B_ * CH) / 128;
    constexpr int Q = (12 * GY) / 8;
    int f = blockIdx.x + blockIdx.y * 12;
    int w = (f & 7) * Q + (f >> 3);
    bx = w % 12; by = w / 12; }
  const int m0 = by * 128;
  const int n0 = bx * 128;

#pragma unroll
  for (int i = 0; i < 8; i++) {               // stage x tile 128x64
    int idx = t + i * 256;
    int row = idx >> 4, c4 = idx & 15;
    int r = m0 + row;
    size_t xrow = (size_t)(r / CH) * S_ + s0 + (r % CH);
    float4 v = *(const float4*)(x + xrow * D_ + c4 * 4);
    *(float4*)(&xs[row][c4 * 4]) = v;
  }
#pragma unroll
  for (int i = 0; i < 8; i++) {               // stage W1 tile 64x128
    int idx = t + i * 256;
    int row = idx >> 5, c4 = idx & 31;
    float4 v = *(const float4*)(W1 + (size_t)row * N3_ + n0 + c4 * 4);
    *(float4*)(&wsh[row][c4 * 4]) = v;
  }
  __syncthreads();

  const int rt = t >> 4, ct = t & 15;
  float acc[8][8];
#pragma unroll
  for (int i = 0; i < 8; i++)
#pragma unroll
    for (int j = 0; j < 8; j++) acc[i][j] = 0.f;

#pragma unroll 4
  for (int k = 0; k < 64; k++) {
    float4 q0 = *(const float4*)(&wsh[k][ct * 8]);
    float4 q1 = *(const float4*)(&wsh[k][ct * 8 + 4]);
    float bq[8] = {q0.x, q0.y, q0.z, q0.w, q1.x, q1.y, q1.z, q1.w};
#pragma unroll
    for (int i = 0; i < 8; i++) {
      float av = xs[rt + 16 * i][k];
#pragma unroll
      for (int j = 0; j < 8; j++) acc[i][j] = fmaf(av, bq[j], acc[i][j]);
    }
  }

  const bool isz = (n0 < 512);
  float bvals[8];
#pragma unroll
  for (int j = 0; j < 8; j++) bvals[j] = b1[n0 + ct * 8 + j];
#pragma unroll
  for (int i = 0; i < 8; i++) {
    const int m = m0 + rt + 16 * i;
    u32 w[4];
#pragma unroll
    for (int jj = 0; jj < 4; jj++) {
      float g0 = acc[i][2 * jj] + bvals[2 * jj];
      float g1v = acc[i][2 * jj + 1] + bvals[2 * jj + 1];
      float v0 = isz ? tanh_safe(g0) : sigm(g0);
      float v1 = isz ? tanh_safe(g1v) : sigm(g1v);
      w[jj] = (u32)f2bf(v0) | ((u32)f2bf(v1) << 16);
    }
    uint4 sv; sv.x = w[0]; sv.y = w[1]; sv.z = w[2]; sv.w = w[3];
    *(uint4*)(g1 + (size_t)m * N3_ + n0 + ct * 8) = sv;
  }
}

// ---------------------------------------------------------------------------
// scan1c<CH>: fo-pool layer1 over one chunk. thread=(b,h). h1c = o*c.
// ---------------------------------------------------------------------------
template <int CH>
__global__ __launch_bounds__(256) void scan1c(const u16* __restrict__ g1,
                                              u16* __restrict__ h1c,
                                              float* __restrict__ c1, int first) {
  const int tid = blockIdx.x * 256 + threadIdx.x;
  const int b = tid >> 9, h = tid & 511;
  const u16* A = g1 + (size_t)b * CH * N3_ + h;
  u16* O = h1c + (size_t)b * CH * H_ + h;
  float c = first ? 0.f : c1[tid];
#pragma unroll 8
  for (int ds = 0; ds < CH; ds++) {
    const u16* p = A + (size_t)ds * N3_;
    float za = bf2f(p[0]);
    float fa = bf2f(p[512]);
    float oa = bf2f(p[1024]);
    c = fmaf(fa, c - za, za);          // f*c + (1-f)*z
    O[(size_t)ds * H_] = f2bf(oa * c);
  }
  c1[tid] = c;
}

// ---------------------------------------------------------------------------
// gemm2c<CH>: bf16 MFMA GEMM + act, N=1024 (z,f). Tile 128x128, BK=32,
// global_load_lds double-buffer (2-phase), XOR-swizzled LDS, LDS epilogue.
// ---------------------------------------------------------------------------
template <int CH>
__global__ __launch_bounds__(256) void gemm2c(const u16* __restrict__ h1c,
                                              const u16* __restrict__ w2t,
                                              const float* __restrict__ b2,
                                              u16* __restrict__ g2) {
  __shared__ __align__(16) u16 As[2][128 * 32];
  __shared__ __align__(16) u16 Bs[2][128 * 32];
  const int t = threadIdx.x;
  const int l = t & 63, wv = t >> 6;
  const int wm = wv >> 1, wn = wv & 1;
  const int lr = l & 15, lg = l >> 4;

  int bx, by;                                   // XCD-aware swizzle (bijective)
  { constexpr int GY = (B_ * CH) / 128;
    constexpr int Q = (8 * GY) / 8;
    int f = blockIdx.x + blockIdx.y * 8;
    int w = (f & 7) * Q + (f >> 3);
    bx = w & 7; by = w >> 3; }
  const int m0 = by * 128, n0 = bx * 128;

  // Staging: LDS dest linear (wave-uniform base + lane*16); global source
  // per-lane, seg pre-XOR'd so swizzled ds_reads see the right data.
  u32 gA[2], gB[2], ldsO[2];
#pragma unroll
  for (int q2 = 0; q2 < 2; q2++) {
    int row = (wv * 2 + q2) * 16 + (l >> 2);
    int pseg = l & 3;
    int lseg = pseg ^ ((row & 3) ^ ((row >> 2) & 3));
    gA[q2] = (u32)(m0 + row) * H_ + lseg * 8;
    gB[q2] = (u32)(n0 + row) * H_ + lseg * 8;
    ldsO[q2] = (u32)(wv * 2 + q2) * 16 * 32;    // u16 units, wave-uniform
  }
  int aoff[4], boff[4];
#pragma unroll
  for (int i = 0; i < 4; i++) {
    aoff[i] = swz_off(wm * 64 + i * 16 + lr, lg);
    boff[i] = swz_off(wn * 64 + i * 16 + lr, lg);
  }

  const f32x4 zero4 = {0.f, 0.f, 0.f, 0.f};
  f32x4 acc[4][4];
#pragma unroll
  for (int i = 0; i < 4; i++)
#pragma unroll
    for (int j = 0; j < 4; j++) acc[i][j] = zero4;

#define STAGE(bi, kt) do {                                                     \
    const u32 ko = (u32)(kt) * 32;                                             \
    _Pragma("unroll")                                                          \
    for (int q2 = 0; q2 < 2; q2++) {                                           \
      __builtin_amdgcn_global_load_lds(                                        \
          (const __attribute__((address_space(1))) void*)(h1c + gA[q2] + ko),  \
          (__attribute__((address_space(3))) void*)(&As[bi][ldsO[q2]]), 16, 0, 0); \
      __builtin_amdgcn_global_load_lds(                                        \
          (const __attribute__((address_space(1))) void*)(w2t + gB[q2] + ko),  \
          (__attribute__((address_space(3))) void*)(&Bs[bi][ldsO[q2]]), 16, 0, 0); \
    } } while (0)

  STAGE(0, 0);
  __syncthreads();
  for (int kt = 0; kt < 16; kt++) {
    const int cur = kt & 1;
    if (kt < 15) STAGE(cur ^ 1, kt + 1);
    bf16x8 af[4], bfr[4];
#pragma unroll
    for (int i = 0; i < 4; i++) af[i] = *(const bf16x8*)((const char*)As[cur] + aoff[i]);
#pragma unroll
    for (int j = 0; j < 4; j++) bfr[j] = *(const bf16x8*)((const char*)Bs[cur] + boff[j]);
#pragma unroll
    for (int i = 0; i < 4; i++)
#pragma unroll
      for (int j = 0; j < 4; j++)
        acc[i][j] = __builtin_amdgcn_mfma_f32_16x16x32_bf16(af[i], bfr[j], acc[i][j], 0, 0, 0);
    __syncthreads();   // drains vmcnt (next tile staged) + lgkmcnt
  }
#undef STAGE

  // Epilogue: act+bias, transpose via LDS (row stride 72 u16 = 144B),
  // then one aligned uint4 (8 bf16) store per lane per pass -> full 64B lines.
  u16* ep = (u16*)&As[0][0];
  u16* myep = ep + wv * 1152;                   // 16 rows * 72 u16
  const bool isz = (n0 < 512);
  float bvv[4];
#pragma unroll
  for (int j = 0; j < 4; j++) bvv[j] = b2[n0 + wn * 64 + j * 16 + lr];
#pragma unroll
  for (int i = 0; i < 4; i++) {
#pragma unroll
    for (int j = 0; j < 4; j++)
#pragma unroll
      for (int r = 0; r < 4; r++) {
        float g = acc[i][j][r] + bvv[j];
        float v = isz ? tanh_safe(g) : sigm(g);
        myep[(lg * 4 + r) * 72 + j * 16 + lr] = f2bf(v);
      }
    // wave reads only its own area: no barrier needed (in-thread lgkmcnt)
#pragma unroll
    for (int p = 0; p < 2; p++) {
      int row = l >> 2, seg = (l & 3) + p * 4;
      uint4 v = *(const uint4*)(myep + row * 72 + seg * 8);
      int m = m0 + wm * 64 + i * 16 + row;
      *(uint4*)(g2 + (size_t)m * N2_ + n0 + wn * 64 + seg * 8) = v;
    }
    __syncthreads();                            // safe reuse of myep across i
  }
}

// ---------------------------------------------------------------------------
// o_last_k<CH>: o-gate only for the 128 rows at s = S-1 (last chunk's
// ds = CH-1). out olast[b][h] = sigmoid(h1_last(b,:) . W2[:,1024+h] + b2).
// ---------------------------------------------------------------------------
template <int CH>
__global__ __launch_bounds__(256) void o_last_k(const u16* __restrict__ h1c,
                                                const u16* __restrict__ w2t,
                                                const float* __restrict__ b2,
                                                float* __restrict__ olast) {
  __shared__ float hs[H_];
  const int b = blockIdx.x;
  const u16* hrow = h1c + ((size_t)b * CH + CH - 1) * H_;
  for (int k = threadIdx.x; k < H_; k += 256) hs[k] = bf2f(hrow[k]);
  __syncthreads();
  for (int n = threadIdx.x; n < H_; n += 256) {
    const u16* wr = w2t + (size_t)(1024 + n) * H_;
    float acc = 0.f;
#pragma unroll 8
    for (int k = 0; k < H_; k++) acc = fmaf(hs[k], bf2f(wr[k]), acc);
    olast[(size_t)b * H_ + n] = sigm(acc + b2[1024 + n]);
  }
}

// ---------------------------------------------------------------------------
// scan2c<CH>: fo-pool layer2 over one chunk (z,f planes, stride N2_).
// ---------------------------------------------------------------------------
template <int CH>
__global__ __launch_bounds__(256) void scan2c(const u16* __restrict__ g2,
                                              float* __restrict__ c2,
                                              const float* __restrict__ olast,
                                              float* __restrict__ h2l,
                                              int first, int last) {
  const int tid = blockIdx.x * 256 + threadIdx.x;
  const int b = tid >> 9, h = tid & 511;
  const u16* A = g2 + (size_t)b * CH * N2_ + h;
  float c = first ? 0.f : c2[tid];
#pragma unroll 8
  for (int ds = 0; ds < CH; ds++) {
    const u16* p = A + (size_t)ds * N2_;
    float za = bf2f(p[0]);
    float fa = bf2f(p[512]);
    c = fmaf(fa, c - za, za);
  }
  c2[tid] = c;
  if (last) h2l[tid] = olast[tid] * c;
}

// ---------------------------------------------------------------------------
// final_fc: out = h2_last @ Wfc + bfc.  (128x512)@(512x64) fp32.
// ---------------------------------------------------------------------------
__global__ __launch_bounds__(256) void final_fc(const float* __restrict__ h2l,
                                                const float* __restrict__ Wfc,
                                                const float* __restrict__ bfc,
                                                float* __restrict__ out) {
  __shared__ float red[4][64];
  const int b = blockIdx.x;
  const int t = threadIdx.x, d = t & 63, q = t >> 6;
  const float* hrow = h2l + (size_t)b * H_;
  float acc = 0.f;
#pragma unroll 4
  for (int h = q * 128; h < (q + 1) * 128; h++)
    acc = fmaf(hrow[h], Wfc[(size_t)h * D_ + d], acc);
  red[q][d] = acc;
  __syncthreads();
  if (q == 0)
    out[(size_t)b * D_ + d] = red[0][d] + red[1][d] + red[2][d] + red[3][d] + bfc[d];
}

// ---------------------------------------------------------------------------
template <int CH>
static void run_pipeline(const float* x, const float* W1, const float* b1,
                         const float* W2, const float* b2,
                         const float* Wfc, const float* bfc,
                         float* out, char* ws, hipStream_t stream) {
  constexpr size_t G1B  = (size_t)B_ * CH * N3_ * 2;
  constexpr size_t H1B  = (size_t)B_ * CH * H_ * 2;
  constexpr size_t G2B  = (size_t)B_ * CH * N2_ * 2;
  constexpr size_t W2TB = (size_t)N3_ * H_ * 2;
  u16*   g1    = (u16*)(ws);
  u16*   h1c   = (u16*)(ws + G1B);
  u16*   g2    = (u16*)(ws + G1B + H1B);
  u16*   w2t   = (u16*)(ws + G1B + H1B + G2B);
  float* c1    = (float*)(ws + G1B + H1B + G2B + W2TB);
  float* c2    = c1 + (size_t)B_ * H_;
  float* olast = c2 + (size_t)B_ * H_;
  float* h2l   = olast + (size_t)B_ * H_;

  k0_w2t<<<dim3(N3_ / 64, H_ / 64), 256, 0, stream>>>(W2, w2t);
  constexpr int NC = S_ / CH;
  for (int i = 0; i < NC; i++) {
    const int s0 = i * CH;
    gemm1c<CH><<<dim3(12, (B_ * CH) / 128), 256, 0, stream>>>(x, W1, b1, g1, s0);
    scan1c<CH><<<(B_ * H_) / 256, 256, 0, stream>>>(g1, h1c, c1, i == 0);
    if (i == NC - 1)
      o_last_k<CH><<<B_, 256, 0, stream>>>(h1c, w2t, b2, olast);
    gemm2c<CH><<<dim3(8, (B_ * CH) / 128), 256, 0, stream>>>(h1c, w2t, b2, g2);
    scan2c<CH><<<(B_ * H_) / 256, 256, 0, stream>>>(g2, c2, olast, h2l, i == 0, i == NC - 1);
  }
  final_fc<<<B_, 256, 0, stream>>>(h2l, Wfc, bfc, out);
}

extern "C" void kernel_launch(void* const* d_in, const int* in_sizes, int n_in,
                              void* d_out, int out_size, void* d_ws, size_t ws_size,
                              hipStream_t stream) {
  (void)in_sizes; (void)n_in; (void)out_size;
  const float* x   = (const float*)d_in[0];
  const float* W1  = (const float*)d_in[1];
  const float* b1  = (const float*)d_in[2];
  const float* W2  = (const float*)d_in[3];
  const float* b2  = (const float*)d_in[4];
  const float* Wfc = (const float*)d_in[5];
  const float* bfc = (const float*)d_in[6];
  float* out = (float*)d_out;
  char* ws = (char*)d_ws;

  // peak ws need: CH=128 -> 103,284,736 B ; CH=32 -> 27,787,264 B
  if (ws_size >= 103284736ull)
    run_pipeline<128>(x, W1, b1, W2, b2, Wfc, bfc, out, ws, stream);
  else
    run_pipeline<32>(x, W1, b1, W2, b2, Wfc, bfc, out, ws, stream);
}

// Round 5
// 769.299 us; speedup vs baseline: 2.2011x; 1.3225x over previous
//
#include <hip/hip_runtime.h>

// ---------------------------------------------------------------------------
// QRNN (window=1, fo-pool) on MI355X — round 3 (resubmit; round-4 bench was
// an infra timeout, no data).
// Both GEMMs bf16 MFMA 16x16x32 with global_load_lds staging (linear LDS
// dest + pre-swizzled per-lane global src), XOR-swizzled ds_read_b128,
// LDS-transposed epilogue, XCD-aware block swizzle.
// gemm2: ring-3 LDS, prefetch depth 2, counted s_waitcnt vmcnt(4) (T4).
// ws (CH=128): g1g2 50.3M (g2 aliases g1) + h1c 16.8M + xbf 16.8M + w2t 1.6M
//              + w1t 0.2M + carries 1.0M = 86,704,128 B.
// ---------------------------------------------------------------------------

using u16 = unsigned short;
using u32 = unsigned int;

typedef __attribute__((ext_vector_type(8))) short bf16x8;
typedef __attribute__((ext_vector_type(4))) float f32x4;

#define B_  128
#define S_  1024
#define D_  64
#define H_  512
#define N3_ 1536
#define N2_ 1024   // gemm2 output cols (z,f only)

__device__ __forceinline__ u16 f2bf(float f) {        // RNE float->bf16
  u32 u = __builtin_bit_cast(u32, f);
  u = (u + 0x7fffu + ((u >> 16) & 1u)) >> 16;
  return (u16)u;
}
__device__ __forceinline__ float bf2f(u16 h) {
  u32 u = ((u32)h) << 16;
  return __builtin_bit_cast(float, u);
}
__device__ __forceinline__ float sigm(float x) {
  return 1.f / (1.f + __expf(-x));
}
__device__ __forceinline__ float tanh_safe(float x) {
  float ax = fabsf(x);
  float t = __expf(-2.f * ax);                        // in (0,1]
  float r = (1.f - t) / (1.f + t);                    // always finite
  return copysignf(r, x);
}
__device__ __forceinline__ int swz_off(int row, int seg) {  // byte off, 64B rows
  return row * 64 + (((seg ^ (row & 3) ^ ((row >> 2) & 3)) & 3) << 4);
}

// ---------------------------------------------------------------------------
// one-offs: x -> bf16; W1 -> w1t [1536][64] bf16; W2 -> w2t [1536][512] bf16
// ---------------------------------------------------------------------------
__global__ __launch_bounds__(256) void k_xcast(const float* __restrict__ x,
                                               u16* __restrict__ xbf) {
  const int nq = B_ * S_ * D_ / 4;                    // 2,097,152 float4 quads
  for (int q = blockIdx.x * 256 + threadIdx.x; q < nq; q += 1024 * 256) {
    float4 v = ((const float4*)x)[q];
    uint2 o;
    o.x = (u32)f2bf(v.x) | ((u32)f2bf(v.y) << 16);
    o.y = (u32)f2bf(v.z) | ((u32)f2bf(v.w) << 16);
    ((uint2*)xbf)[q] = o;
  }
}

__global__ __launch_bounds__(256) void k0_w1t(const float* __restrict__ W1,
                                              u16* __restrict__ w1t) {
  __shared__ u16 tile[64][65];
  const int n0 = blockIdx.x * 64;
  const int t = threadIdx.x;
  const int c = t & 63, r0 = t >> 6;
#pragma unroll
  for (int i = 0; i < 16; i++) {
    int r = r0 + i * 4;                               // k index 0..63
    tile[r][c] = f2bf(W1[(size_t)r * N3_ + n0 + c]);
  }
  __syncthreads();
#pragma unroll
  for (int i = 0; i < 16; i++) {
    int cc = r0 + i * 4;
    w1t[(size_t)(n0 + cc) * 64 + c] = tile[c][cc];    // w1t[n][k] = W1[k][n]
  }
}

__global__ __launch_bounds__(256) void k0_w2t(const float* __restrict__ W2,
                                              u16* __restrict__ w2t) {
  __shared__ u16 tile[64][65];
  const int n0 = blockIdx.x * 64, k0 = blockIdx.y * 64;
  const int t = threadIdx.x;
  const int c = t & 63, r0 = t >> 6;
#pragma unroll
  for (int i = 0; i < 16; i++) {
    int r = r0 + i * 4;
    tile[r][c] = f2bf(W2[(size_t)(k0 + r) * N3_ + n0 + c]);
  }
  __syncthreads();
#pragma unroll
  for (int i = 0; i < 16; i++) {
    int cc = r0 + i * 4;
    w2t[(size_t)(n0 + cc) * H_ + k0 + c] = tile[c][cc];
  }
}

// ---------------------------------------------------------------------------
// gemm1m<CH>: bf16 MFMA GEMM + act, K=64 (2 K-steps, both prefetched).
// A = xbf rows (chunk mapping), B = w1t. Output g1 [M][1536] post-activation.
// ---------------------------------------------------------------------------
template <int CH>
__global__ __launch_bounds__(256) void gemm1m(const u16* __restrict__ xbf,
                                              const u16* __restrict__ w1t,
                                              const float* __restrict__ b1,
                                              u16* __restrict__ g1, int s0) {
  __shared__ __align__(16) u16 As[2][128 * 32];
  __shared__ __align__(16) u16 Bs[2][128 * 32];
  const int t = threadIdx.x;
  const int l = t & 63, wv = t >> 6;
  const int wm = wv >> 1, wn = wv & 1;
  const int lr = l & 15, lg = l >> 4;

  int bx, by;                                   // XCD-aware swizzle (bijective)
  { constexpr int GX = 12, GY = (B_ * CH) / 128;
    constexpr int Q = (GX * GY) / 8;
    int f = blockIdx.x + blockIdx.y * GX;
    int w = (f & 7) * Q + (f >> 3);
    bx = w % GX; by = w / GX; }
  const int m0 = by * 128, n0 = bx * 128;

  u32 gA[2], gB[2], ldsO[2];
#pragma unroll
  for (int q2 = 0; q2 < 2; q2++) {
    int row = (wv * 2 + q2) * 16 + (l >> 2);
    int pseg = l & 3;
    int lseg = pseg ^ ((row & 3) ^ ((row >> 2) & 3));
    int r = m0 + row;
    u32 xrow = (u32)(r / CH) * S_ + s0 + (r % CH);
    gA[q2] = xrow * 64 + lseg * 8;
    gB[q2] = (u32)(n0 + row) * 64 + lseg * 8;
    ldsO[q2] = (u32)(wv * 2 + q2) * 16 * 32;    // u16 units, wave-uniform
  }
  int aoff[4], boff[4];
#pragma unroll
  for (int i = 0; i < 4; i++) {
    aoff[i] = swz_off(wm * 64 + i * 16 + lr, lg);
    boff[i] = swz_off(wn * 64 + i * 16 + lr, lg);
  }
  const bool isz = (n0 < 512);
  float bvv[4];
#pragma unroll
  for (int j = 0; j < 4; j++) bvv[j] = b1[n0 + wn * 64 + j * 16 + lr];

  const f32x4 zero4 = {0.f, 0.f, 0.f, 0.f};
  f32x4 acc[4][4];
#pragma unroll
  for (int i = 0; i < 4; i++)
#pragma unroll
    for (int j = 0; j < 4; j++) acc[i][j] = zero4;

#define STAGE1(bi, kt) do {                                                    \
    const u32 ko = (u32)(kt) * 32;                                             \
    _Pragma("unroll")                                                          \
    for (int q2 = 0; q2 < 2; q2++) {                                           \
      __builtin_amdgcn_global_load_lds(                                        \
          (const __attribute__((address_space(1))) void*)(xbf + gA[q2] + ko),  \
          (__attribute__((address_space(3))) void*)(&As[bi][ldsO[q2]]), 16, 0, 0); \
      __builtin_amdgcn_global_load_lds(                                        \
          (const __attribute__((address_space(1))) void*)(w1t + gB[q2] + ko),  \
          (__attribute__((address_space(3))) void*)(&Bs[bi][ldsO[q2]]), 16, 0, 0); \
    } } while (0)

  STAGE1(0, 0);
  STAGE1(1, 1);
#pragma unroll
  for (int kt = 0; kt < 2; kt++) {
    if (kt == 0) asm volatile("s_waitcnt vmcnt(4)" ::: "memory");
    else         asm volatile("s_waitcnt vmcnt(0)" ::: "memory");
    __builtin_amdgcn_s_barrier();
    bf16x8 af[4], bfr[4];
#pragma unroll
    for (int i = 0; i < 4; i++) af[i] = *(const bf16x8*)((const char*)As[kt] + aoff[i]);
#pragma unroll
    for (int j = 0; j < 4; j++) bfr[j] = *(const bf16x8*)((const char*)Bs[kt] + boff[j]);
#pragma unroll
    for (int i = 0; i < 4; i++)
#pragma unroll
      for (int j = 0; j < 4; j++)
        acc[i][j] = __builtin_amdgcn_mfma_f32_16x16x32_bf16(af[i], bfr[j], acc[i][j], 0, 0, 0);
  }
#undef STAGE1
  __syncthreads();                              // all reads done before epilogue reuse

  // Epilogue: act+bias, LDS transpose (rows 72 u16), 16B stores.
  u16* myep = (u16*)&As[0][0] + wv * 1152;
#pragma unroll
  for (int i = 0; i < 4; i++) {
#pragma unroll
    for (int j = 0; j < 4; j++)
#pragma unroll
      for (int r = 0; r < 4; r++) {
        float g = acc[i][j][r] + bvv[j];
        float v = isz ? tanh_safe(g) : sigm(g);
        myep[(lg * 4 + r) * 72 + j * 16 + lr] = f2bf(v);
      }
#pragma unroll
    for (int p = 0; p < 2; p++) {
      int row = l >> 2, seg = (l & 3) + p * 4;
      uint4 v = *(const uint4*)(myep + row * 72 + seg * 8);
      int m = m0 + wm * 64 + i * 16 + row;
      *(uint4*)(g1 + (size_t)m * N3_ + n0 + wn * 64 + seg * 8) = v;
    }
    __syncthreads();
  }
}

// ---------------------------------------------------------------------------
// scan1c<CH>: fo-pool layer1 over one chunk. thread=(b,h). h1c = o*c.
// ---------------------------------------------------------------------------
template <int CH>
__global__ __launch_bounds__(256) void scan1c(const u16* __restrict__ g1,
                                              u16* __restrict__ h1c,
                                              float* __restrict__ c1, int first) {
  const int tid = blockIdx.x * 256 + threadIdx.x;
  const int b = tid >> 9, h = tid & 511;
  const u16* A = g1 + (size_t)b * CH * N3_ + h;
  u16* O = h1c + (size_t)b * CH * H_ + h;
  float c = first ? 0.f : c1[tid];
#pragma unroll 8
  for (int ds = 0; ds < CH; ds++) {
    const u16* p = A + (size_t)ds * N3_;
    float za = bf2f(p[0]);
    float fa = bf2f(p[512]);
    float oa = bf2f(p[1024]);
    c = fmaf(fa, c - za, za);          // f*c + (1-f)*z
    O[(size_t)ds * H_] = f2bf(oa * c);
  }
  c1[tid] = c;
}

// ---------------------------------------------------------------------------
// gemm2c<CH>: bf16 MFMA GEMM + act, N=1024 (z,f), K=512. Ring-3 LDS,
// prefetch depth 2, counted vmcnt(4), one barrier per K-step.
// ---------------------------------------------------------------------------
template <int CH>
__global__ __launch_bounds__(256) void gemm2c(const u16* __restrict__ h1c,
                                              const u16* __restrict__ w2t,
                                              const float* __restrict__ b2,
                                              u16* __restrict__ g2) {
  __shared__ __align__(16) u16 As[3][128 * 32];
  __shared__ __align__(16) u16 Bs[3][128 * 32];
  const int t = threadIdx.x;
  const int l = t & 63, wv = t >> 6;
  const int wm = wv >> 1, wn = wv & 1;
  const int lr = l & 15, lg = l >> 4;

  int bx, by;                                   // XCD-aware swizzle (bijective)
  { constexpr int GY = (B_ * CH) / 128;
    constexpr int Q = (8 * GY) / 8;
    int f = blockIdx.x + blockIdx.y * 8;
    int w = (f & 7) * Q + (f >> 3);
    bx = w & 7; by = w >> 3; }
  const int m0 = by * 128, n0 = bx * 128;

  u32 gA[2], gB[2], ldsO[2];
#pragma unroll
  for (int q2 = 0; q2 < 2; q2++) {
    int row = (wv * 2 + q2) * 16 + (l >> 2);
    int pseg = l & 3;
    int lseg = pseg ^ ((row & 3) ^ ((row >> 2) & 3));
    gA[q2] = (u32)(m0 + row) * H_ + lseg * 8;
    gB[q2] = (u32)(n0 + row) * H_ + lseg * 8;
    ldsO[q2] = (u32)(wv * 2 + q2) * 16 * 32;    // u16 units, wave-uniform
  }
  int aoff[4], boff[4];
#pragma unroll
  for (int i = 0; i < 4; i++) {
    aoff[i] = swz_off(wm * 64 + i * 16 + lr, lg);
    boff[i] = swz_off(wn * 64 + i * 16 + lr, lg);
  }
  const bool isz = (n0 < 512);
  float bvv[4];
#pragma unroll
  for (int j = 0; j < 4; j++) bvv[j] = b2[n0 + wn * 64 + j * 16 + lr];

  const f32x4 zero4 = {0.f, 0.f, 0.f, 0.f};
  f32x4 acc[4][4];
#pragma unroll
  for (int i = 0; i < 4; i++)
#pragma unroll
    for (int j = 0; j < 4; j++) acc[i][j] = zero4;

#define STAGE2(bi, kt) do {                                                    \
    const u32 ko = (u32)(kt) * 32;                                             \
    _Pragma("unroll")                                                          \
    for (int q2 = 0; q2 < 2; q2++) {                                           \
      __builtin_amdgcn_global_load_lds(                                        \
          (const __attribute__((address_space(1))) void*)(h1c + gA[q2] + ko),  \
          (__attribute__((address_space(3))) void*)(&As[bi][ldsO[q2]]), 16, 0, 0); \
      __builtin_amdgcn_global_load_lds(                                        \
          (const __attribute__((address_space(1))) void*)(w2t + gB[q2] + ko),  \
          (__attribute__((address_space(3))) void*)(&Bs[bi][ldsO[q2]]), 16, 0, 0); \
    } } while (0)

  STAGE2(0, 0);
  STAGE2(1, 1);
  for (int kt = 0; kt < 16; kt++) {
    // stage(kt) must be complete; stage(kt+1)'s 4 loads may stay in flight.
    if (kt < 15) asm volatile("s_waitcnt vmcnt(4)" ::: "memory");
    else         asm volatile("s_waitcnt vmcnt(0)" ::: "memory");
    __builtin_amdgcn_s_barrier();
    const int cur = kt % 3;
    bf16x8 af[4], bfr[4];
#pragma unroll
    for (int i = 0; i < 4; i++) af[i] = *(const bf16x8*)((const char*)As[cur] + aoff[i]);
#pragma unroll
    for (int j = 0; j < 4; j++) bfr[j] = *(const bf16x8*)((const char*)Bs[cur] + boff[j]);
    if (kt < 14) STAGE2((kt + 2) % 3, kt + 2);  // writes buf consumed at kt-1: safe post-barrier
#pragma unroll
    for (int i = 0; i < 4; i++)
#pragma unroll
      for (int j = 0; j < 4; j++)
        acc[i][j] = __builtin_amdgcn_mfma_f32_16x16x32_bf16(af[i], bfr[j], acc[i][j], 0, 0, 0);
  }
#undef STAGE2
  __syncthreads();                              // all reads done before epilogue reuse

  u16* myep = (u16*)&As[0][0] + wv * 1152;      // 16 rows * 72 u16 per wave
#pragma unroll
  for (int i = 0; i < 4; i++) {
#pragma unroll
    for (int j = 0; j < 4; j++)
#pragma unroll
      for (int r = 0; r < 4; r++) {
        float g = acc[i][j][r] + bvv[j];
        float v = isz ? tanh_safe(g) : sigm(g);
        myep[(lg * 4 + r) * 72 + j * 16 + lr] = f2bf(v);
      }
#pragma unroll
    for (int p = 0; p < 2; p++) {
      int row = l >> 2, seg = (l & 3) + p * 4;
      uint4 v = *(const uint4*)(myep + row * 72 + seg * 8);
      int m = m0 + wm * 64 + i * 16 + row;
      *(uint4*)(g2 + (size_t)m * N2_ + n0 + wn * 64 + seg * 8) = v;
    }
    __syncthreads();
  }
}

// ---------------------------------------------------------------------------
// o_last_k<CH>: o-gate only for the 128 rows at s = S-1.
// ---------------------------------------------------------------------------
template <int CH>
__global__ __launch_bounds__(256) void o_last_k(const u16* __restrict__ h1c,
                                                const u16* __restrict__ w2t,
                                                const float* __restrict__ b2,
                                                float* __restrict__ olast) {
  __shared__ float hs[H_];
  const int b = blockIdx.x;
  const u16* hrow = h1c + ((size_t)b * CH + CH - 1) * H_;
  for (int k = threadIdx.x; k < H_; k += 256) hs[k] = bf2f(hrow[k]);
  __syncthreads();
  for (int n = threadIdx.x; n < H_; n += 256) {
    const u16* wr = w2t + (size_t)(1024 + n) * H_;
    float acc = 0.f;
#pragma unroll 8
    for (int k = 0; k < H_; k++) acc = fmaf(hs[k], bf2f(wr[k]), acc);
    olast[(size_t)b * H_ + n] = sigm(acc + b2[1024 + n]);
  }
}

// ---------------------------------------------------------------------------
// scan2c<CH>: fo-pool layer2 over one chunk (z,f planes, stride N2_).
// ---------------------------------------------------------------------------
template <int CH>
__global__ __launch_bounds__(256) void scan2c(const u16* __restrict__ g2,
                                              float* __restrict__ c2,
                                              const float* __restrict__ olast,
                                              float* __restrict__ h2l,
                                              int first, int last) {
  const int tid = blockIdx.x * 256 + threadIdx.x;
  const int b = tid >> 9, h = tid & 511;
  const u16* A = g2 + (size_t)b * CH * N2_ + h;
  float c = first ? 0.f : c2[tid];
#pragma unroll 8
  for (int ds = 0; ds < CH; ds++) {
    const u16* p = A + (size_t)ds * N2_;
    float za = bf2f(p[0]);
    float fa = bf2f(p[512]);
    c = fmaf(fa, c - za, za);
  }
  c2[tid] = c;
  if (last) h2l[tid] = olast[tid] * c;
}

// ---------------------------------------------------------------------------
// final_fc: out = h2_last @ Wfc + bfc.  (128x512)@(512x64) fp32.
// ---------------------------------------------------------------------------
__global__ __launch_bounds__(256) void final_fc(const float* __restrict__ h2l,
                                                const float* __restrict__ Wfc,
                                                const float* __restrict__ bfc,
                                                float* __restrict__ out) {
  __shared__ float red[4][64];
  const int b = blockIdx.x;
  const int t = threadIdx.x, d = t & 63, q = t >> 6;
  const float* hrow = h2l + (size_t)b * H_;
  float acc = 0.f;
#pragma unroll 4
  for (int h = q * 128; h < (q + 1) * 128; h++)
    acc = fmaf(hrow[h], Wfc[(size_t)h * D_ + d], acc);
  red[q][d] = acc;
  __syncthreads();
  if (q == 0)
    out[(size_t)b * D_ + d] = red[0][d] + red[1][d] + red[2][d] + red[3][d] + bfc[d];
}

// ---------------------------------------------------------------------------
template <int CH>
static void run_pipeline(const float* x, const float* W1, const float* b1,
                         const float* W2, const float* b2,
                         const float* Wfc, const float* bfc,
                         float* out, char* ws, hipStream_t stream) {
  constexpr size_t G1B  = (size_t)B_ * CH * N3_ * 2;   // g1 (g2 aliases base)
  constexpr size_t H1B  = (size_t)B_ * CH * H_ * 2;
  constexpr size_t XBFB = (size_t)B_ * S_ * D_ * 2;    // 16,777,216
  constexpr size_t W2TB = (size_t)N3_ * H_ * 2;        // 1,572,864
  constexpr size_t W1TB = (size_t)N3_ * D_ * 2;        // 196,608
  u16*   g1    = (u16*)(ws);
  u16*   g2    = g1;                                   // alias: g1 dead after scan1
  u16*   h1c   = (u16*)(ws + G1B);
  u16*   xbf   = (u16*)(ws + G1B + H1B);
  u16*   w2t   = (u16*)(ws + G1B + H1B + XBFB);
  u16*   w1t   = (u16*)(ws + G1B + H1B + XBFB + W2TB);
  float* c1    = (float*)(ws + G1B + H1B + XBFB + W2TB + W1TB);
  float* c2    = c1 + (size_t)B_ * H_;
  float* olast = c2 + (size_t)B_ * H_;
  float* h2l   = olast + (size_t)B_ * H_;

  k_xcast<<<1024, 256, 0, stream>>>(x, xbf);
  k0_w1t <<<N3_ / 64, 256, 0, stream>>>(W1, w1t);
  k0_w2t <<<dim3(N3_ / 64, H_ / 64), 256, 0, stream>>>(W2, w2t);
  constexpr int NC = S_ / CH;
  for (int i = 0; i < NC; i++) {
    const int s0 = i * CH;
    gemm1m<CH><<<dim3(12, (B_ * CH) / 128), 256, 0, stream>>>(xbf, w1t, b1, g1, s0);
    scan1c<CH><<<(B_ * H_) / 256, 256, 0, stream>>>(g1, h1c, c1, i == 0);
    if (i == NC - 1)
      o_last_k<CH><<<B_, 256, 0, stream>>>(h1c, w2t, b2, olast);
    gemm2c<CH><<<dim3(8, (B_ * CH) / 128), 256, 0, stream>>>(h1c, w2t, b2, g2);
    scan2c<CH><<<(B_ * H_) / 256, 256, 0, stream>>>(g2, c2, olast, h2l, i == 0, i == NC - 1);
  }
  final_fc<<<B_, 256, 0, stream>>>(h2l, Wfc, bfc, out);
}

extern "C" void kernel_launch(void* const* d_in, const int* in_sizes, int n_in,
                              void* d_out, int out_size, void* d_ws, size_t ws_size,
                              hipStream_t stream) {
  (void)in_sizes; (void)n_in; (void)out_size;
  const float* x   = (const float*)d_in[0];
  const float* W1  = (const float*)d_in[1];
  const float* b1  = (const float*)d_in[2];
  const float* W2  = (const float*)d_in[3];
  const float* b2  = (const float*)d_in[4];
  const float* Wfc = (const float*)d_in[5];
  const float* bfc = (const float*)d_in[6];
  float* out = (float*)d_out;
  char* ws = (char*)d_ws;

  // peak ws need: CH=128 -> 86,704,128 B ; CH=32 -> 36,372,480 B
  if (ws_size >= 86704128ull)
    run_pipeline<128>(x, W1, b1, W2, b2, Wfc, bfc, out, ws, stream);
  else
    run_pipeline<32>(x, W1, b1, W2, b2, Wfc, bfc, out, ws, stream);
}

// Round 6
// 677.253 us; speedup vs baseline: 2.5002x; 1.1359x over previous
//
#include <hip/hip_runtime.h>

// ---------------------------------------------------------------------------
// QRNN (window=1, fo-pool) on MI355X — round 6: pipelined fat dispatches.
// GEMMs store RAW pre-activations (bias added); scans apply tanh/sigm
// (VALU hidden under scan memory latency).
// Dispatch pipeline (CH=64, NC=16):
//   prek: xcast + w1t + w2t (one kernel, block ranges)
//   for i in 0..NC:  gemmd(i) = gemm2(chunk i-1) ∥ gemm1(chunk i) ∥ olast@i==NC
//                    scand(i) = scan1(chunk i)  ∥ scan2(chunk i-1)
//   final_fc
// ws (CH=64): g1 25.2M + g2 16.8M + h1c 8.4M + xbf 16.8M + w2t 1.6M
//             + w1t 0.2M + carries 1.0M = 69,926,912 B (< proven 103.3M).
// ---------------------------------------------------------------------------

using u16 = unsigned short;
using u32 = unsigned int;

typedef __attribute__((ext_vector_type(8))) short bf16x8;
typedef __attribute__((ext_vector_type(4))) float f32x4;

#define B_  128
#define S_  1024
#define D_  64
#define H_  512
#define N3_ 1536
#define N2_ 1024   // gemm2 output cols (z,f only)

__device__ __forceinline__ u16 f2bf(float f) {        // RNE float->bf16
  u32 u = __builtin_bit_cast(u32, f);
  u = (u + 0x7fffu + ((u >> 16) & 1u)) >> 16;
  return (u16)u;
}
__device__ __forceinline__ float bf2f(u16 h) {
  u32 u = ((u32)h) << 16;
  return __builtin_bit_cast(float, u);
}
__device__ __forceinline__ float sigm(float x) {
  return 1.f / (1.f + __expf(-x));
}
__device__ __forceinline__ float tanh_safe(float x) {
  float ax = fabsf(x);
  float t = __expf(-2.f * ax);                        // in (0,1]
  float r = (1.f - t) / (1.f + t);                    // always finite
  return copysignf(r, x);
}
__device__ __forceinline__ int swz_off(int row, int seg) {  // byte off, 64B rows
  return row * 64 + (((seg ^ (row & 3) ^ ((row >> 2) & 3)) & 3) << 4);
}

// ---------------------------------------------------------------------------
// prek: [0,1024) x->bf16 ; [1024,1048) W1->w1t ; [1048,1240) W2->w2t
// ---------------------------------------------------------------------------
__global__ __launch_bounds__(256) void prek(const float* __restrict__ x,
                                            u16* __restrict__ xbf,
                                            const float* __restrict__ W1,
                                            u16* __restrict__ w1t,
                                            const float* __restrict__ W2,
                                            u16* __restrict__ w2t) {
  __shared__ u16 tile[64][65];
  const int bid = blockIdx.x;
  const int t = threadIdx.x;
  if (bid < 1024) {                                   // xcast
    const int nq = B_ * S_ * D_ / 4;
    for (int q = bid * 256 + t; q < nq; q += 1024 * 256) {
      float4 v = ((const float4*)x)[q];
      uint2 o;
      o.x = (u32)f2bf(v.x) | ((u32)f2bf(v.y) << 16);
      o.y = (u32)f2bf(v.z) | ((u32)f2bf(v.w) << 16);
      ((uint2*)xbf)[q] = o;
    }
    return;
  }
  const int c = t & 63, r0 = t >> 6;
  if (bid < 1048) {                                   // w1t: [1536][64]
    const int n0 = (bid - 1024) * 64;
#pragma unroll
    for (int i = 0; i < 16; i++) {
      int r = r0 + i * 4;
      tile[r][c] = f2bf(W1[(size_t)r * N3_ + n0 + c]);
    }
    __syncthreads();
#pragma unroll
    for (int i = 0; i < 16; i++) {
      int cc = r0 + i * 4;
      w1t[(size_t)(n0 + cc) * 64 + c] = tile[c][cc];
    }
    return;
  }
  {                                                   // w2t: [1536][512]
    const int j = bid - 1048;
    const int n0 = (j % 24) * 64, k0 = (j / 24) * 64;
#pragma unroll
    for (int i = 0; i < 16; i++) {
      int r = r0 + i * 4;
      tile[r][c] = f2bf(W2[(size_t)(k0 + r) * N3_ + n0 + c]);
    }
    __syncthreads();
#pragma unroll
    for (int i = 0; i < 16; i++) {
      int cc = r0 + i * 4;
      w2t[(size_t)(n0 + cc) * H_ + k0 + c] = tile[c][cc];
    }
  }
}

// ---------------------------------------------------------------------------
// gemmd<CH>: fat GEMM dispatch.
//   blocks [0,ng2): gemm2 (chunk i-1), [ng2,ng2+ng1): gemm1 (chunk i),
//   [ng2+ng1, +nol): o_last.
// Both GEMMs: bf16 MFMA 16x16x32, 128x128 tile, 4 waves 2x2, gload_lds
// staging (linear LDS dest + pre-XOR'd global src), XOR-swizzled ds_read,
// LDS-transposed epilogue with bias (NO activation).
// ---------------------------------------------------------------------------
template <int CH>
__global__ __launch_bounds__(256) void gemmd(
    const u16* __restrict__ xbf, const u16* __restrict__ w1t,
    const float* __restrict__ b1, u16* __restrict__ g1, int s0_g1, int ng1,
    const u16* __restrict__ h1c, const u16* __restrict__ w2t,
    const float* __restrict__ b2, u16* __restrict__ g2, int ng2,
    float* __restrict__ olast, int nol) {
  __shared__ __align__(16) u16 shm[6 * 4096];         // 49152 B
  const int t = threadIdx.x;
  const int l = t & 63, wv = t >> 6;
  const int wm = wv >> 1, wn = wv & 1;
  const int lr = l & 15, lg = l >> 4;
  constexpr int GY = (B_ * CH) / 128;                 // m-tiles per chunk
  int bid = blockIdx.x;

  if (bid < ng2) {
    // ---------------- gemm2: [M=B*CH x 1024] = h1c[.,512] @ w2t ------------
    int bx, by;
    { int w = (bid & 7) * GY + (bid >> 3); bx = w & 7; by = w >> 3; }
    const int m0 = by * 128, n0 = bx * 128;
    u16* As = shm;                                    // 3 bufs x 4096
    u16* Bs = shm + 3 * 4096;

    u32 gA[2], gB[2], ldsO[2];
#pragma unroll
    for (int q2 = 0; q2 < 2; q2++) {
      int row = (wv * 2 + q2) * 16 + (l >> 2);
      int lseg = (l & 3) ^ ((row & 3) ^ ((row >> 2) & 3));
      gA[q2] = (u32)(m0 + row) * H_ + lseg * 8;
      gB[q2] = (u32)(n0 + row) * H_ + lseg * 8;
      ldsO[q2] = (u32)(wv * 2 + q2) * 512;            // 16 rows * 32 u16
    }
    int aoff[4], boff[4];
#pragma unroll
    for (int i = 0; i < 4; i++) {
      aoff[i] = swz_off(wm * 64 + i * 16 + lr, lg);
      boff[i] = swz_off(wn * 64 + i * 16 + lr, lg);
    }
    float bvv[4];
#pragma unroll
    for (int j = 0; j < 4; j++) bvv[j] = b2[n0 + wn * 64 + j * 16 + lr];

    const f32x4 zero4 = {0.f, 0.f, 0.f, 0.f};
    f32x4 acc[4][4];
#pragma unroll
    for (int i = 0; i < 4; i++)
#pragma unroll
      for (int j = 0; j < 4; j++) acc[i][j] = zero4;

#define STAGE2(bi, kt) do {                                                    \
    const u32 ko = (u32)(kt) * 32;                                             \
    _Pragma("unroll")                                                          \
    for (int q2 = 0; q2 < 2; q2++) {                                           \
      __builtin_amdgcn_global_load_lds(                                        \
          (const __attribute__((address_space(1))) void*)(h1c + gA[q2] + ko),  \
          (__attribute__((address_space(3))) void*)(As + (bi) * 4096 + ldsO[q2]), 16, 0, 0); \
      __builtin_amdgcn_global_load_lds(                                        \
          (const __attribute__((address_space(1))) void*)(w2t + gB[q2] + ko),  \
          (__attribute__((address_space(3))) void*)(Bs + (bi) * 4096 + ldsO[q2]), 16, 0, 0); \
    } } while (0)

    STAGE2(0, 0);
    STAGE2(1, 1);
    for (int kt = 0; kt < 16; kt++) {
      if (kt < 15) asm volatile("s_waitcnt vmcnt(4)" ::: "memory");
      else         asm volatile("s_waitcnt vmcnt(0)" ::: "memory");
      __builtin_amdgcn_s_barrier();
      const int cur = kt % 3;
      bf16x8 af[4], bfr[4];
#pragma unroll
      for (int i = 0; i < 4; i++)
        af[i] = *(const bf16x8*)((const char*)(As + cur * 4096) + aoff[i]);
#pragma unroll
      for (int j = 0; j < 4; j++)
        bfr[j] = *(const bf16x8*)((const char*)(Bs + cur * 4096) + boff[j]);
      if (kt < 14) STAGE2((kt + 2) % 3, kt + 2);      // buf read at kt-1: safe
#pragma unroll
      for (int i = 0; i < 4; i++)
#pragma unroll
        for (int j = 0; j < 4; j++)
          acc[i][j] = __builtin_amdgcn_mfma_f32_16x16x32_bf16(af[i], bfr[j], acc[i][j], 0, 0, 0);
    }
#undef STAGE2
    __syncthreads();
    // epilogue: bias only, LDS transpose (72-u16 rows), 16B stores
    u16* myep = shm + wv * 1152;
#pragma unroll
    for (int i = 0; i < 4; i++) {
#pragma unroll
      for (int j = 0; j < 4; j++)
#pragma unroll
        for (int r = 0; r < 4; r++)
          myep[(lg * 4 + r) * 72 + j * 16 + lr] = f2bf(acc[i][j][r] + bvv[j]);
#pragma unroll
      for (int p = 0; p < 2; p++) {
        int row = l >> 2, seg = (l & 3) + p * 4;
        uint4 v = *(const uint4*)(myep + row * 72 + seg * 8);
        int m = m0 + wm * 64 + i * 16 + row;
        *(uint4*)(g2 + (size_t)m * N2_ + n0 + wn * 64 + seg * 8) = v;
      }
    }
    return;
  }
  bid -= ng2;

  if (bid < ng1) {
    // ---------------- gemm1: [M x 1536] = xbf(chunk) @ w1t, K=64 -----------
    int bx, by;
    { constexpr int Q = (12 * GY) / 8;
      int w = (bid & 7) * Q + (bid >> 3);
      bx = w % 12; by = w / 12; }
    const int m0 = by * 128, n0 = bx * 128;
    u16* As = shm;                                    // 2 bufs x 4096
    u16* Bs = shm + 2 * 4096;

    u32 gA[2], gB[2], ldsO[2];
#pragma unroll
    for (int q2 = 0; q2 < 2; q2++) {
      int row = (wv * 2 + q2) * 16 + (l >> 2);
      int lseg = (l & 3) ^ ((row & 3) ^ ((row >> 2) & 3));
      int r = m0 + row;
      u32 xrow = (u32)(r / CH) * S_ + s0_g1 + (r % CH);
      gA[q2] = xrow * 64 + lseg * 8;
      gB[q2] = (u32)(n0 + row) * 64 + lseg * 8;
      ldsO[q2] = (u32)(wv * 2 + q2) * 512;
    }
    int aoff[4], boff[4];
#pragma unroll
    for (int i = 0; i < 4; i++) {
      aoff[i] = swz_off(wm * 64 + i * 16 + lr, lg);
      boff[i] = swz_off(wn * 64 + i * 16 + lr, lg);
    }
    float bvv[4];
#pragma unroll
    for (int j = 0; j < 4; j++) bvv[j] = b1[n0 + wn * 64 + j * 16 + lr];

    const f32x4 zero4 = {0.f, 0.f, 0.f, 0.f};
    f32x4 acc[4][4];
#pragma unroll
    for (int i = 0; i < 4; i++)
#pragma unroll
      for (int j = 0; j < 4; j++) acc[i][j] = zero4;

#define STAGE1(bi, kt) do {                                                    \
    const u32 ko = (u32)(kt) * 32;                                             \
    _Pragma("unroll")                                                          \
    for (int q2 = 0; q2 < 2; q2++) {                                           \
      __builtin_amdgcn_global_load_lds(                                        \
          (const __attribute__((address_space(1))) void*)(xbf + gA[q2] + ko),  \
          (__attribute__((address_space(3))) void*)(As + (bi) * 4096 + ldsO[q2]), 16, 0, 0); \
      __builtin_amdgcn_global_load_lds(                                        \
          (const __attribute__((address_space(1))) void*)(w1t + gB[q2] + ko),  \
          (__attribute__((address_space(3))) void*)(Bs + (bi) * 4096 + ldsO[q2]), 16, 0, 0); \
    } } while (0)

    STAGE1(0, 0);
    STAGE1(1, 1);
#pragma unroll
    for (int kt = 0; kt < 2; kt++) {
      if (kt == 0) asm volatile("s_waitcnt vmcnt(4)" ::: "memory");
      else         asm volatile("s_waitcnt vmcnt(0)" ::: "memory");
      __builtin_amdgcn_s_barrier();
      bf16x8 af[4], bfr[4];
#pragma unroll
      for (int i = 0; i < 4; i++)
        af[i] = *(const bf16x8*)((const char*)(As + kt * 4096) + aoff[i]);
#pragma unroll
      for (int j = 0; j < 4; j++)
        bfr[j] = *(const bf16x8*)((const char*)(Bs + kt * 4096) + boff[j]);
#pragma unroll
      for (int i = 0; i < 4; i++)
#pragma unroll
        for (int j = 0; j < 4; j++)
          acc[i][j] = __builtin_amdgcn_mfma_f32_16x16x32_bf16(af[i], bfr[j], acc[i][j], 0, 0, 0);
    }
#undef STAGE1
    __syncthreads();
    u16* myep = shm + wv * 1152;
#pragma unroll
    for (int i = 0; i < 4; i++) {
#pragma unroll
      for (int j = 0; j < 4; j++)
#pragma unroll
        for (int r = 0; r < 4; r++)
          myep[(lg * 4 + r) * 72 + j * 16 + lr] = f2bf(acc[i][j][r] + bvv[j]);
#pragma unroll
      for (int p = 0; p < 2; p++) {
        int row = l >> 2, seg = (l & 3) + p * 4;
        uint4 v = *(const uint4*)(myep + row * 72 + seg * 8);
        int m = m0 + wm * 64 + i * 16 + row;
        *(uint4*)(g1 + (size_t)m * N3_ + n0 + wn * 64 + seg * 8) = v;
      }
    }
    return;
  }
  bid -= ng1;

  if (bid < nol) {
    // ---------------- o_last: sigmoid(h1_last @ W2[:,1024+n] + b2) ---------
    __shared__ float hs[H_];
    const int b = bid;
    const u16* hrow = h1c + ((size_t)b * CH + CH - 1) * H_;
    for (int k = t; k < H_; k += 256) hs[k] = bf2f(hrow[k]);
    __syncthreads();
    for (int n = t; n < H_; n += 256) {
      const u16* wr = w2t + (size_t)(1024 + n) * H_;
      float acc = 0.f;
#pragma unroll 8
      for (int k = 0; k < H_; k++) acc = fmaf(hs[k], bf2f(wr[k]), acc);
      olast[(size_t)b * H_ + n] = sigm(acc + b2[1024 + n]);
    }
  }
}

// ---------------------------------------------------------------------------
// scand<CH>: blocks [0,ns1): scan1 chunk i (raw g1 -> act -> fo-pool -> h1c);
//            blocks [ns1, ns1+ns2): scan2 chunk i-1 (raw g2 -> act -> carry).
// ---------------------------------------------------------------------------
template <int CH>
__global__ __launch_bounds__(256) void scand(
    const u16* __restrict__ g1, u16* __restrict__ h1c, float* __restrict__ c1,
    int ns1, int first1,
    const u16* __restrict__ g2, float* __restrict__ c2,
    const float* __restrict__ olast, float* __restrict__ h2l,
    int first2, int last2) {
  int bid = blockIdx.x;
  if (bid < ns1) {
    const int tid = bid * 256 + threadIdx.x;
    const int b = tid >> 9, h = tid & 511;
    const u16* A = g1 + (size_t)b * CH * N3_ + h;
    u16* O = h1c + (size_t)b * CH * H_ + h;
    float c = first1 ? 0.f : c1[tid];
#pragma unroll 4
    for (int ds = 0; ds < CH; ds++) {
      const u16* p = A + (size_t)ds * N3_;
      float za = tanh_safe(bf2f(p[0]));
      float fa = sigm(bf2f(p[512]));
      float oa = sigm(bf2f(p[1024]));
      c = fmaf(fa, c - za, za);          // f*c + (1-f)*z
      O[(size_t)ds * H_] = f2bf(oa * c);
    }
    c1[tid] = c;
    return;
  }
  bid -= ns1;
  {
    const int tid = bid * 256 + threadIdx.x;
    const int b = tid >> 9, h = tid & 511;
    const u16* A = g2 + (size_t)b * CH * N2_ + h;
    float c = first2 ? 0.f : c2[tid];
#pragma unroll 4
    for (int ds = 0; ds < CH; ds++) {
      const u16* p = A + (size_t)ds * N2_;
      float za = tanh_safe(bf2f(p[0]));
      float fa = sigm(bf2f(p[512]));
      c = fmaf(fa, c - za, za);
    }
    c2[tid] = c;
    if (last2) h2l[tid] = olast[tid] * c;
  }
}

// ---------------------------------------------------------------------------
// final_fc: out = h2_last @ Wfc + bfc.  (128x512)@(512x64) fp32.
// ---------------------------------------------------------------------------
__global__ __launch_bounds__(256) void final_fc(const float* __restrict__ h2l,
                                                const float* __restrict__ Wfc,
                                                const float* __restrict__ bfc,
                                                float* __restrict__ out) {
  __shared__ float red[4][64];
  const int b = blockIdx.x;
  const int t = threadIdx.x, d = t & 63, q = t >> 6;
  const float* hrow = h2l + (size_t)b * H_;
  float acc = 0.f;
#pragma unroll 4
  for (int h = q * 128; h < (q + 1) * 128; h++)
    acc = fmaf(hrow[h], Wfc[(size_t)h * D_ + d], acc);
  red[q][d] = acc;
  __syncthreads();
  if (q == 0)
    out[(size_t)b * D_ + d] = red[0][d] + red[1][d] + red[2][d] + red[3][d] + bfc[d];
}

// ---------------------------------------------------------------------------
template <int CH>
static void run_pipeline(const float* x, const float* W1, const float* b1,
                         const float* W2, const float* b2,
                         const float* Wfc, const float* bfc,
                         float* out, char* ws, hipStream_t stream) {
  constexpr size_t G1B  = (size_t)B_ * CH * N3_ * 2;
  constexpr size_t G2B  = (size_t)B_ * CH * N2_ * 2;
  constexpr size_t H1B  = (size_t)B_ * CH * H_ * 2;
  constexpr size_t XBFB = (size_t)B_ * S_ * D_ * 2;
  constexpr size_t W2TB = (size_t)N3_ * H_ * 2;
  constexpr size_t W1TB = (size_t)N3_ * D_ * 2;
  u16*   g1    = (u16*)(ws);
  u16*   g2    = (u16*)(ws + G1B);
  u16*   h1c   = (u16*)(ws + G1B + G2B);
  u16*   xbf   = (u16*)(ws + G1B + G2B + H1B);
  u16*   w2t   = (u16*)(ws + G1B + G2B + H1B + XBFB);
  u16*   w1t   = (u16*)(ws + G1B + G2B + H1B + XBFB + W2TB);
  float* c1    = (float*)(ws + G1B + G2B + H1B + XBFB + W2TB + W1TB);
  float* c2    = c1 + (size_t)B_ * H_;
  float* olast = c2 + (size_t)B_ * H_;
  float* h2l   = olast + (size_t)B_ * H_;

  prek<<<1240, 256, 0, stream>>>(x, xbf, W1, w1t, W2, w2t);
  constexpr int NC = S_ / CH;
  constexpr int GY = (B_ * CH) / 128;
  for (int i = 0; i <= NC; i++) {
    const int ng1 = (i < NC) ? 12 * GY : 0;
    const int ng2 = (i >= 1) ? 8 * GY : 0;
    const int nol = (i == NC) ? B_ : 0;
    gemmd<CH><<<ng2 + ng1 + nol, 256, 0, stream>>>(
        xbf, w1t, b1, g1, i * CH, ng1, h1c, w2t, b2, g2, ng2, olast, nol);
    const int ns1 = (i < NC) ? 256 : 0;      // B_*H_/256
    const int ns2 = (i >= 1) ? 256 : 0;
    scand<CH><<<ns1 + ns2, 256, 0, stream>>>(
        g1, h1c, c1, ns1, i == 0, g2, c2, olast, h2l, i == 1, i == NC);
  }
  final_fc<<<B_, 256, 0, stream>>>(h2l, Wfc, bfc, out);
}

extern "C" void kernel_launch(void* const* d_in, const int* in_sizes, int n_in,
                              void* d_out, int out_size, void* d_ws, size_t ws_size,
                              hipStream_t stream) {
  (void)in_sizes; (void)n_in; (void)out_size;
  const float* x   = (const float*)d_in[0];
  const float* W1  = (const float*)d_in[1];
  const float* b1  = (const float*)d_in[2];
  const float* W2  = (const float*)d_in[3];
  const float* b2  = (const float*)d_in[4];
  const float* Wfc = (const float*)d_in[5];
  const float* bfc = (const float*)d_in[6];
  float* out = (float*)d_out;
  char* ws = (char*)d_ws;

  // peak ws need: CH=64 -> 69,926,912 B ; CH=32 -> 44,826,624 B
  if (ws_size >= 69926912ull)
    run_pipeline<64>(x, W1, b1, W2, b2, Wfc, bfc, out, ws, stream);
  else
    run_pipeline<32>(x, W1, b1, W2, b2, Wfc, bfc, out, ws, stream);
}

// Round 7
// 585.396 us; speedup vs baseline: 2.8926x; 1.1569x over previous
//
#include <hip/hip_runtime.h>

// ---------------------------------------------------------------------------
// QRNN (window=1, fo-pool) on MI355X — round 7: FULLY FUSED layers.
// fused1: x@W1+b1 -> act -> fo-pool -> h1   (per block: one b, 128-h slice)
// fused2: h1@W2+b2 (z,f cols) -> act -> fo-pool carry only (no per-s output!)
// W-operands live in REGISTERS per wave; LDS = A-ring + zf tile only.
// S processed in 4 quarters (QS=256) sharing one h1 buffer + f32 carries.
// Dispatches: prek + 4x(fused1,fused2) + olast + final_fc = 11.
// ws: h1q 33.55M + w2t 1.57M + w1t 0.20M + c1/c2/olast/h2l 1.05M = 36.4 MB.
// ---------------------------------------------------------------------------

using u16 = unsigned short;
using u32 = unsigned int;

typedef __attribute__((ext_vector_type(8))) short bf16x8;
typedef __attribute__((ext_vector_type(4))) float f32x4;

#define B_  128
#define S_  1024
#define D_  64
#define H_  512
#define N3_ 1536
#define QS_ 256    // s-rows per quarter dispatch

__device__ __forceinline__ u16 f2bf(float f) {        // RNE float->bf16
  u32 u = __builtin_bit_cast(u32, f);
  u = (u + 0x7fffu + ((u >> 16) & 1u)) >> 16;
  return (u16)u;
}
__device__ __forceinline__ float bf2f(u16 h) {
  u32 u = ((u32)h) << 16;
  return __builtin_bit_cast(float, u);
}
__device__ __forceinline__ float sigm(float x) {
  return 1.f / (1.f + __expf(-x));
}
__device__ __forceinline__ float tanh_safe(float x) {
  float ax = fabsf(x);
  float t = __expf(-2.f * ax);                        // in (0,1]
  float r = (1.f - t) / (1.f + t);                    // always finite
  return copysignf(r, x);
}
__device__ __forceinline__ int swz_off(int row, int seg) {  // byte off, 64B rows
  return row * 64 + (((seg ^ (row & 3) ^ ((row >> 2) & 3)) & 3) << 4);
}

#define WAITV4 asm volatile("s_waitcnt vmcnt(4)" ::: "memory")
#define WAITV0 asm volatile("s_waitcnt vmcnt(0)" ::: "memory")
#define WAITL  asm volatile("s_waitcnt lgkmcnt(0)" ::: "memory")
#define SCHED0 __builtin_amdgcn_sched_barrier(0)
#define SBAR   __builtin_amdgcn_s_barrier()

// ---------------------------------------------------------------------------
// prek: [0,24) W1 -> w1t[1536][64] ; [24,216) W2 -> w2t[1536][512]  (bf16)
// ---------------------------------------------------------------------------
__global__ __launch_bounds__(256) void prek(const float* __restrict__ W1,
                                            u16* __restrict__ w1t,
                                            const float* __restrict__ W2,
                                            u16* __restrict__ w2t) {
  __shared__ u16 tile[64][65];
  const int bid = blockIdx.x;
  const int t = threadIdx.x;
  const int c = t & 63, r0 = t >> 6;
  if (bid < 24) {                                     // w1t
    const int n0 = bid * 64;
#pragma unroll
    for (int i = 0; i < 16; i++) {
      int r = r0 + i * 4;
      tile[r][c] = f2bf(W1[(size_t)r * N3_ + n0 + c]);
    }
    __syncthreads();
#pragma unroll
    for (int i = 0; i < 16; i++) {
      int cc = r0 + i * 4;
      w1t[(size_t)(n0 + cc) * 64 + c] = tile[c][cc];
    }
    return;
  }
  {                                                   // w2t
    const int j = bid - 24;
    const int n0 = (j % 24) * 64, k0 = (j / 24) * 64;
#pragma unroll
    for (int i = 0; i < 16; i++) {
      int r = r0 + i * 4;
      tile[r][c] = f2bf(W2[(size_t)(k0 + r) * N3_ + n0 + c]);
    }
    __syncthreads();
#pragma unroll
    for (int i = 0; i < 16; i++) {
      int cc = r0 + i * 4;
      w2t[(size_t)(n0 + cc) * H_ + k0 + c] = tile[c][cc];
    }
  }
}

// ---------------------------------------------------------------------------
// fused1: layer-1 GEMM(K=64, bf16 MFMA) + act + fo-pool, one quarter of S.
// Block = (hr 0..3, b 0..127), bid = hr*128 + b  (b%8 -> XCD affinity).
// Per wave: 6 n-tiles (z/f/o 16-col groups), W1 frags in 12 bf16x8 regs.
// A-ring: x cast to bf16 in regs, ds_write; s-tile = 32 rows.
// Scan: waves 0,1 (128 h), h1 written directly to global.
// ---------------------------------------------------------------------------
__global__ __launch_bounds__(256) void fused1(const float* __restrict__ x,
                                              const u16* __restrict__ w1t,
                                              const float* __restrict__ b1,
                                              u16* __restrict__ h1q,
                                              float* __restrict__ c1,
                                              int s0, int first) {
  constexpr int T = QS_ / 32;
  __shared__ __align__(16) u16 Aring[2][2048];        // [2 ktiles][32 rows][64B]
  __shared__ u16 zfo[32][392];                        // cols: z 0-127, f 128-255, o 256-383
  const int t = threadIdx.x;
  const int l = t & 63, wv = t >> 6;
  const int lr = l & 15, lg = l >> 4;
  const int bid = blockIdx.x;
  const int hr = bid >> 7, b = bid & 127;
  const int hb = hr * 128;

  // B fragments + bias in registers
  bf16x8 breg[6][2];
  float bias[6];
#pragma unroll
  for (int j = 0; j < 6; j++) {
    int jt = wv * 6 + j;
    int col = (jt < 8) ? (hb + jt * 16)
            : (jt < 16) ? (512 + hb + (jt - 8) * 16)
                        : (1024 + hb + (jt - 16) * 16);
    const u16* wp = w1t + (size_t)(col + lr) * 64 + lg * 8;
    breg[j][0] = *(const bf16x8*)(wp);
    breg[j][1] = *(const bf16x8*)(wp + 32);
    bias[j] = b1[col + lr];
  }

  // staging geometry (thread covers 16B slot t of the 4KB tile)
  int srow, ksrc;
  {
    int ktile = t >> 7;
    int w = t & 127;
    int row = w >> 2, pseg = w & 3;
    int lseg = pseg ^ ((row & 3) ^ ((row >> 2) & 3));
    srow = row;
    ksrc = ktile * 32 + lseg * 8;
  }
  const u32 ldsw = (u32)t * 8;                        // u16 idx of slot

  float c = 0.f;
  const int hmy = wv * 64 + l;                        // valid for wv<2
  if (wv < 2 && !first) c = c1[b * 512 + hb + hmy];

  // prologue: stage tile 0
  {
    const float* xp = x + ((size_t)b * S_ + s0 + srow) * 64 + ksrc;
    float4 v0 = *(const float4*)(xp);
    float4 v1 = *(const float4*)(xp + 4);
    uint4 xa;
    xa.x = (u32)f2bf(v0.x) | ((u32)f2bf(v0.y) << 16);
    xa.y = (u32)f2bf(v0.z) | ((u32)f2bf(v0.w) << 16);
    xa.z = (u32)f2bf(v1.x) | ((u32)f2bf(v1.y) << 16);
    xa.w = (u32)f2bf(v1.z) | ((u32)f2bf(v1.w) << 16);
    *(uint4*)(&Aring[0][ldsw]) = xa;
  }
  WAITL; SCHED0; SBAR;

  const f32x4 zero4 = {0.f, 0.f, 0.f, 0.f};
  for (int tt = 0; tt < T; ++tt) {
    const int rb = tt & 1;
    SBAR;                                             // scan(tt-1) done: zfo writable
    // early-issue x loads for tt+1
    float4 v0, v1;
    const bool more = (tt + 1 < T);
    if (more) {
      const float* xp = x + ((size_t)b * S_ + s0 + (tt + 1) * 32 + srow) * 64 + ksrc;
      v0 = *(const float4*)(xp);
      v1 = *(const float4*)(xp + 4);
    }
    // GEMM tile tt: [32 x 384] @ K=64
    f32x4 acc[2][6];
#pragma unroll
    for (int m = 0; m < 2; m++)
#pragma unroll
      for (int j = 0; j < 6; j++) acc[m][j] = zero4;
    const char* Ab = (const char*)&Aring[rb][0];
#pragma unroll
    for (int kk = 0; kk < 2; kk++) {
      bf16x8 a0 = *(const bf16x8*)(Ab + kk * 2048 + swz_off(lr, lg));
      bf16x8 a1 = *(const bf16x8*)(Ab + kk * 2048 + swz_off(16 + lr, lg));
#pragma unroll
      for (int j = 0; j < 6; j++) {
        acc[0][j] = __builtin_amdgcn_mfma_f32_16x16x32_bf16(a0, breg[j][kk], acc[0][j], 0, 0, 0);
        acc[1][j] = __builtin_amdgcn_mfma_f32_16x16x32_bf16(a1, breg[j][kk], acc[1][j], 0, 0, 0);
      }
    }
    // act + zfo write (bf16)
#pragma unroll
    for (int j = 0; j < 6; j++) {
      int jt = wv * 6 + j;
      int colL = (jt < 8) ? (jt * 16) : (jt < 16) ? (128 + (jt - 8) * 16)
                                                  : (256 + (jt - 16) * 16);
      const bool isz = (jt < 8);
#pragma unroll
      for (int m = 0; m < 2; m++)
#pragma unroll
        for (int r = 0; r < 4; r++) {
          float g = acc[m][j][r] + bias[j];
          float v = isz ? tanh_safe(g) : sigm(g);
          zfo[m * 16 + lg * 4 + r][colL + lr] = f2bf(v);
        }
    }
    // stage tt+1 into ring
    if (more) {
      uint4 xb;
      xb.x = (u32)f2bf(v0.x) | ((u32)f2bf(v0.y) << 16);
      xb.y = (u32)f2bf(v0.z) | ((u32)f2bf(v0.w) << 16);
      xb.z = (u32)f2bf(v1.x) | ((u32)f2bf(v1.y) << 16);
      xb.w = (u32)f2bf(v1.z) | ((u32)f2bf(v1.w) << 16);
      *(uint4*)(&Aring[rb ^ 1][ldsw]) = xb;
    }
    WAITL; SCHED0; SBAR;                              // zfo + ring visible
    // scan (waves 0,1: h = hmy)
    if (wv < 2) {
      u16* hout = h1q + ((size_t)b * QS_ + tt * 32) * 512 + hb + hmy;
#pragma unroll 8
      for (int ss = 0; ss < 32; ss++) {
        float z = bf2f(zfo[ss][hmy]);
        float f = bf2f(zfo[ss][128 + hmy]);
        float o = bf2f(zfo[ss][256 + hmy]);
        c = fmaf(f, c - z, z);                        // f*c + (1-f)*z
        hout[(size_t)ss * 512] = f2bf(o * c);
      }
    }
  }
  if (wv < 2) c1[b * 512 + hb + hmy] = c;
}

// ---------------------------------------------------------------------------
// fused2: layer-2 GEMM(K=512) + act + fo-pool carry, one quarter of S.
// Block = (hr 0..15, b 0..127), bid = hr*128 + b. 64 out cols: z(h0..h0+31),
// f(512+h0..). Per wave: ONE 16-col n-tile, W2 frags in 16 bf16x8 regs.
// A-ring: h1 s-tile (16 x 512) via global_load_lds, counted vmcnt.
// Scan: wave 0 lanes 0-31; no per-s output (carry only).
// ---------------------------------------------------------------------------
__global__ __launch_bounds__(256) void fused2(const u16* __restrict__ h1q,
                                              const u16* __restrict__ w2t,
                                              const float* __restrict__ b2,
                                              float* __restrict__ c2,
                                              const float* __restrict__ ol,
                                              float* __restrict__ h2l,
                                              int first, int last) {
  constexpr int T = QS_ / 16;
  __shared__ __align__(16) u16 Aring[2][8192];        // [16 ktiles][16 rows][64B]
  __shared__ float zf[16][68];                        // z cols 0-31, f cols 32-63
  const int t = threadIdx.x;
  const int l = t & 63, wv = t >> 6;
  const int lr = l & 15, lg = l >> 4;
  const int bid = blockIdx.x;
  const int hr = bid >> 7, b = bid & 127;

  // B fragments + bias in registers (wave's n-tile, all K=512)
  const int colb = (wv < 2) ? (hr * 32 + wv * 16) : (512 + hr * 32 + (wv - 2) * 16);
  bf16x8 breg[16];
  {
    const u16* wp = w2t + (size_t)(colb + lr) * 512 + lg * 8;
#pragma unroll
    for (int kk = 0; kk < 16; kk++) breg[kk] = *(const bf16x8*)(wp + kk * 32);
  }
  const float bias = b2[colb + lr];

  // staging offsets: 4 gload_lds calls per tile, thread covers slot per call
  u32 goff[4];
#pragma unroll
  for (int cc = 0; cc < 4; cc++) {
    int o16 = cc * 256 + t;
    int ktile = o16 >> 6;
    int w = o16 & 63;
    int row = w >> 2, pseg = w & 3;
    int lseg = pseg ^ ((row & 3) ^ ((row >> 2) & 3));
    goff[cc] = (u32)((b * QS_ + row) * 512 + ktile * 32 + lseg * 8);
  }
  float c = 0.f;
  if (wv == 0 && l < 32 && !first) c = c2[b * 512 + hr * 32 + l];

#define STG2(rb, tile) do {                                                    \
    _Pragma("unroll")                                                          \
    for (int cc = 0; cc < 4; cc++)                                             \
      __builtin_amdgcn_global_load_lds(                                        \
        (const __attribute__((address_space(1))) void*)(h1q + goff[cc] + (tile) * 16 * 512), \
        (__attribute__((address_space(3))) void*)(&Aring[rb][cc * 2048 + wv * 512]), 16, 0, 0); \
  } while (0)

  WAITV0;                                             // drain breg/c2 loads from vmcnt
  STG2(0, 0);

  for (int tt = 0; tt < T; ++tt) {
    const int rb = tt & 1;
    if (tt + 1 < T) { STG2(rb ^ 1, tt + 1); WAITV4; }
    else            { WAITV0; }
    SCHED0; SBAR;                                     // ring[rb] ready; zf writable (scan tt-1 done)

    f32x4 acc = {0.f, 0.f, 0.f, 0.f};
    const char* Ab = (const char*)&Aring[rb][0];
#pragma unroll
    for (int kk = 0; kk < 16; kk++) {
      bf16x8 af = *(const bf16x8*)(Ab + kk * 1024 + swz_off(lr, lg));
      acc = __builtin_amdgcn_mfma_f32_16x16x32_bf16(af, breg[kk], acc, 0, 0, 0);
    }
#pragma unroll
    for (int r = 0; r < 4; r++) {
      float g = acc[r] + bias;
      float v = (wv < 2) ? tanh_safe(g) : sigm(g);
      zf[lg * 4 + r][wv * 16 + lr] = v;
    }
    WAITL; SCHED0; SBAR;                              // zf visible
    if (wv == 0 && l < 32) {
#pragma unroll
      for (int ss = 0; ss < 16; ss++) {
        float z = zf[ss][l], f = zf[ss][32 + l];
        c = fmaf(f, c - z, z);
      }
    }
  }
#undef STG2
  if (wv == 0 && l < 32) {
    const int idx = b * 512 + hr * 32 + l;
    c2[idx] = c;
    if (last) h2l[idx] = ol[idx] * c;
  }
}

// ---------------------------------------------------------------------------
// o_last_k: o2-gate for the 128 rows at s = S-1 (last quarter, row QS-1).
// ---------------------------------------------------------------------------
__global__ __launch_bounds__(256) void o_last_k(const u16* __restrict__ h1q,
                                                const u16* __restrict__ w2t,
                                                const float* __restrict__ b2,
                                                float* __restrict__ olast) {
  __shared__ float hs[H_];
  const int b = blockIdx.x;
  const u16* hrow = h1q + ((size_t)b * QS_ + QS_ - 1) * H_;
  for (int k = threadIdx.x; k < H_; k += 256) hs[k] = bf2f(hrow[k]);
  __syncthreads();
  for (int n = threadIdx.x; n < H_; n += 256) {
    const u16* wr = w2t + (size_t)(1024 + n) * H_;
    float acc = 0.f;
#pragma unroll 8
    for (int k = 0; k < H_; k++) acc = fmaf(hs[k], bf2f(wr[k]), acc);
    olast[(size_t)b * H_ + n] = sigm(acc + b2[1024 + n]);
  }
}

// ---------------------------------------------------------------------------
// final_fc: out = h2_last @ Wfc + bfc.  (128x512)@(512x64) fp32.
// ---------------------------------------------------------------------------
__global__ __launch_bounds__(256) void final_fc(const float* __restrict__ h2l,
                                                const float* __restrict__ Wfc,
                                                const float* __restrict__ bfc,
                                                float* __restrict__ out) {
  __shared__ float red[4][64];
  const int b = blockIdx.x;
  const int t = threadIdx.x, d = t & 63, q = t >> 6;
  const float* hrow = h2l + (size_t)b * H_;
  float acc = 0.f;
#pragma unroll 4
  for (int h = q * 128; h < (q + 1) * 128; h++)
    acc = fmaf(hrow[h], Wfc[(size_t)h * D_ + d], acc);
  red[q][d] = acc;
  __syncthreads();
  if (q == 0)
    out[(size_t)b * D_ + d] = red[0][d] + red[1][d] + red[2][d] + red[3][d] + bfc[d];
}

// ---------------------------------------------------------------------------
extern "C" void kernel_launch(void* const* d_in, const int* in_sizes, int n_in,
                              void* d_out, int out_size, void* d_ws, size_t ws_size,
                              hipStream_t stream) {
  (void)in_sizes; (void)n_in; (void)out_size; (void)ws_size;
  const float* x   = (const float*)d_in[0];
  const float* W1  = (const float*)d_in[1];
  const float* b1  = (const float*)d_in[2];
  const float* W2  = (const float*)d_in[3];
  const float* b2  = (const float*)d_in[4];
  const float* Wfc = (const float*)d_in[5];
  const float* bfc = (const float*)d_in[6];
  float* out = (float*)d_out;
  char* ws = (char*)d_ws;

  // ws layout (36,372,480 B total; proven ws_size >= 103 MB)
  u16*   h1q   = (u16*)(ws);                          // 33,554,432
  u16*   w2t   = (u16*)(ws + 33554432ull);            //  1,572,864
  u16*   w1t   = (u16*)(ws + 35127296ull);            //    196,608
  float* c1    = (float*)(ws + 35323904ull);          //    262,144
  float* c2    = (float*)(ws + 35586048ull);          //    262,144
  float* olast = (float*)(ws + 35848192ull);          //    262,144
  float* h2l   = (float*)(ws + 36110336ull);          //    262,144

  prek<<<216, 256, 0, stream>>>(W1, w1t, W2, w2t);
  constexpr int NQ = S_ / QS_;                        // 4
  for (int q = 0; q < NQ; q++) {
    fused1<<<4 * 128, 256, 0, stream>>>(x, w1t, b1, h1q, c1, q * QS_, q == 0);
    if (q == NQ - 1)
      o_last_k<<<B_, 256, 0, stream>>>(h1q, w2t, b2, olast);
    fused2<<<16 * 128, 256, 0, stream>>>(h1q, w2t, b2, c2, olast, h2l,
                                         q == 0, q == NQ - 1);
  }
  final_fc<<<B_, 256, 0, stream>>>(h2l, Wfc, bfc, out);
}

// Round 8
// 572.185 us; speedup vs baseline: 2.9593x; 1.0231x over previous
//
#include <hip/hip_runtime.h>

// ---------------------------------------------------------------------------
// QRNN fo-pool, MI355X — round 8.
// Fix: round-7 fused2 had VGPR_Count=52 => breg (W2 frags) were NOT register-
// resident (bare launch_bounds(256) made the compiler re-fetch B every tile).
// Now: __launch_bounds__(256,2) (VGPR budget 256), wave owns z+f of its own
// 16-h slice (breg z+f = 128 VGPR), split acc chains (4x8-deep), ring-3 LDS
// with single barrier/tile + zf double-buffer, per-wave scan (no wave-0 skew).
// ws: h1q 33.55M + w2t 1.57M + w1t 0.20M + carries 1.05M = 36.4 MB.
// ---------------------------------------------------------------------------

using u16 = unsigned short;
using u32 = unsigned int;

typedef __attribute__((ext_vector_type(8))) short bf16x8;
typedef __attribute__((ext_vector_type(4))) float f32x4;

#define B_  128
#define S_  1024
#define D_  64
#define H_  512
#define N3_ 1536
#define QS_ 256    // s-rows per quarter dispatch

__device__ __forceinline__ u16 f2bf(float f) {        // RNE float->bf16
  u32 u = __builtin_bit_cast(u32, f);
  u = (u + 0x7fffu + ((u >> 16) & 1u)) >> 16;
  return (u16)u;
}
__device__ __forceinline__ float bf2f(u16 h) {
  u32 u = ((u32)h) << 16;
  return __builtin_bit_cast(float, u);
}
__device__ __forceinline__ float sigm(float x) {
  return 1.f / (1.f + __expf(-x));
}
__device__ __forceinline__ float tanh_safe(float x) {
  float ax = fabsf(x);
  float t = __expf(-2.f * ax);                        // in (0,1]
  float r = (1.f - t) / (1.f + t);                    // always finite
  return copysignf(r, x);
}
__device__ __forceinline__ int swz_off(int row, int seg) {  // byte off, 64B rows
  return row * 64 + (((seg ^ (row & 3) ^ ((row >> 2) & 3)) & 3) << 4);
}

#define WAITV8 asm volatile("s_waitcnt vmcnt(8)" ::: "memory")
#define WAITV4 asm volatile("s_waitcnt vmcnt(4)" ::: "memory")
#define WAITV0 asm volatile("s_waitcnt vmcnt(0)" ::: "memory")
#define WAITL  asm volatile("s_waitcnt lgkmcnt(0)" ::: "memory")
#define SCHED0 __builtin_amdgcn_sched_barrier(0)
#define SBAR   __builtin_amdgcn_s_barrier()

// ---------------------------------------------------------------------------
// prek: [0,24) W1 -> w1t[1536][64] ; [24,216) W2 -> w2t[1536][512]  (bf16)
// ---------------------------------------------------------------------------
__global__ __launch_bounds__(256) void prek(const float* __restrict__ W1,
                                            u16* __restrict__ w1t,
                                            const float* __restrict__ W2,
                                            u16* __restrict__ w2t) {
  __shared__ u16 tile[64][65];
  const int bid = blockIdx.x;
  const int t = threadIdx.x;
  const int c = t & 63, r0 = t >> 6;
  if (bid < 24) {                                     // w1t
    const int n0 = bid * 64;
#pragma unroll
    for (int i = 0; i < 16; i++) {
      int r = r0 + i * 4;
      tile[r][c] = f2bf(W1[(size_t)r * N3_ + n0 + c]);
    }
    __syncthreads();
#pragma unroll
    for (int i = 0; i < 16; i++) {
      int cc = r0 + i * 4;
      w1t[(size_t)(n0 + cc) * 64 + c] = tile[c][cc];
    }
    return;
  }
  {                                                   // w2t
    const int j = bid - 24;
    const int n0 = (j % 24) * 64, k0 = (j / 24) * 64;
#pragma unroll
    for (int i = 0; i < 16; i++) {
      int r = r0 + i * 4;
      tile[r][c] = f2bf(W2[(size_t)(k0 + r) * N3_ + n0 + c]);
    }
    __syncthreads();
#pragma unroll
    for (int i = 0; i < 16; i++) {
      int cc = r0 + i * 4;
      w2t[(size_t)(n0 + cc) * H_ + k0 + c] = tile[c][cc];
    }
  }
}

// ---------------------------------------------------------------------------
// fused1: layer-1 GEMM(K=64) + act + fo-pool, one quarter of S.
// Block = (hr 0..7, b 0..127): 64-h slice. Wave wv owns z,f,o of its 16-h
// sub-slice (breg[3][2] = 24 VGPR). Tiles of 32 s-rows, T=8.
// Per-wave scan (lanes 0-15), two barriers/tile (ring-2 safe).
// ---------------------------------------------------------------------------
__global__ __launch_bounds__(256, 2) void fused1(const float* __restrict__ x,
                                                 const u16* __restrict__ w1t,
                                                 const float* __restrict__ b1,
                                                 u16* __restrict__ h1q,
                                                 float* __restrict__ c1,
                                                 int s0, int first) {
  constexpr int T = QS_ / 32;                         // 8
  __shared__ __align__(16) u16 Aring[2][2048];        // [2 ktile][32 rows][64B]
  __shared__ u16 zfb[32 * 132];                       // row*132 + h*2 (+1 f)
  __shared__ u16 ob[32 * 68];                         // row*68 + h
  const int t = threadIdx.x;
  const int l = t & 63, wv = t >> 6;
  const int lr = l & 15, lg = l >> 4;
  const int bid = blockIdx.x;
  const int hr = bid >> 7, b = bid & 127;
  const int hb = hr * 64;
  const int hw = hb + wv * 16;                        // wave's h base

  // B fragments + bias (z,f,o for this wave's 16 h)
  bf16x8 breg[3][2];
  float bias[3];
#pragma unroll
  for (int g = 0; g < 3; g++) {
    const int col = g * 512 + hw;
    const u16* wp = w1t + (size_t)(col + lr) * 64 + lg * 8;
    breg[g][0] = *(const bf16x8*)(wp);
    breg[g][1] = *(const bf16x8*)(wp + 32);
    bias[g] = b1[col + lr];
  }
  float c = 0.f;
  if (l < 16 && !first) c = c1[b * 512 + hw + l];

  // staging geometry: thread t covers 16B slot t of the 4KB tile
  int srow, ksrc;
  {
    int ktile = t >> 7;
    int w = t & 127;
    int row = w >> 2, pseg = w & 3;
    int lseg = pseg ^ ((row & 3) ^ ((row >> 2) & 3));
    srow = row;
    ksrc = ktile * 32 + lseg * 8;
  }
  const u32 ldsw = (u32)t * 8;

  {                                                   // stage tile 0
    const float* xp = x + ((size_t)b * S_ + s0 + srow) * 64 + ksrc;
    float4 v0 = *(const float4*)(xp);
    float4 v1 = *(const float4*)(xp + 4);
    uint4 xa;
    xa.x = (u32)f2bf(v0.x) | ((u32)f2bf(v0.y) << 16);
    xa.y = (u32)f2bf(v0.z) | ((u32)f2bf(v0.w) << 16);
    xa.z = (u32)f2bf(v1.x) | ((u32)f2bf(v1.y) << 16);
    xa.w = (u32)f2bf(v1.z) | ((u32)f2bf(v1.w) << 16);
    *(uint4*)(&Aring[0][ldsw]) = xa;
  }
  WAITL; SCHED0; SBAR;

  const f32x4 zero4 = {0.f, 0.f, 0.f, 0.f};
  for (int tt = 0; tt < T; ++tt) {
    const int rb = tt & 1;
    SBAR;                                             // scan(tt-1) done: zf/ob writable
    float4 v0, v1;
    const bool more = (tt + 1 < T);
    if (more) {                                       // prefetch x(tt+1)
      const float* xp = x + ((size_t)b * S_ + s0 + (tt + 1) * 32 + srow) * 64 + ksrc;
      v0 = *(const float4*)(xp);
      v1 = *(const float4*)(xp + 4);
    }
    f32x4 acc[2][3];
#pragma unroll
    for (int m = 0; m < 2; m++)
#pragma unroll
      for (int g = 0; g < 3; g++) acc[m][g] = zero4;
    const char* Ab = (const char*)&Aring[rb][0];
#pragma unroll
    for (int kk = 0; kk < 2; kk++) {
      bf16x8 a0 = *(const bf16x8*)(Ab + kk * 2048 + swz_off(lr, lg));
      bf16x8 a1 = *(const bf16x8*)(Ab + kk * 2048 + swz_off(16 + lr, lg));
#pragma unroll
      for (int g = 0; g < 3; g++) {
        acc[0][g] = __builtin_amdgcn_mfma_f32_16x16x32_bf16(a0, breg[g][kk], acc[0][g], 0, 0, 0);
        acc[1][g] = __builtin_amdgcn_mfma_f32_16x16x32_bf16(a1, breg[g][kk], acc[1][g], 0, 0, 0);
      }
    }
    // act + LDS handoff (z,f packed u32; o u16)
#pragma unroll
    for (int m = 0; m < 2; m++)
#pragma unroll
      for (int r = 0; r < 4; r++) {
        const int row = m * 16 + lg * 4 + r;
        float zv = tanh_safe(acc[m][0][r] + bias[0]);
        float fv = sigm(acc[m][1][r] + bias[1]);
        float ov = sigm(acc[m][2][r] + bias[2]);
        *(u32*)(&zfb[row * 132 + (wv * 16 + lr) * 2]) =
            (u32)f2bf(zv) | ((u32)f2bf(fv) << 16);
        ob[row * 68 + wv * 16 + lr] = f2bf(ov);
      }
    if (more) {                                       // stage tt+1
      uint4 xa;
      xa.x = (u32)f2bf(v0.x) | ((u32)f2bf(v0.y) << 16);
      xa.y = (u32)f2bf(v0.z) | ((u32)f2bf(v0.w) << 16);
      xa.z = (u32)f2bf(v1.x) | ((u32)f2bf(v1.y) << 16);
      xa.w = (u32)f2bf(v1.z) | ((u32)f2bf(v1.w) << 16);
      *(uint4*)(&Aring[rb ^ 1][ldsw]) = xa;
    }
    WAITL; SCHED0; SBAR;                              // zf/ob + ring visible
    // per-wave scan: lanes 0-15 own h = hw + l
    if (l < 16) {
      u16* hout = h1q + ((size_t)b * QS_ + tt * 32) * 512 + hw + l;
      const u16* zrow = &zfb[(wv * 16 + l) * 2];
      const u16* orow = &ob[wv * 16 + l];
#pragma unroll 8
      for (int ss = 0; ss < 32; ss++) {
        u32 v = *(const u32*)(zrow + ss * 132);
        float z = bf2f((u16)v), f = bf2f((u16)(v >> 16));
        float o = bf2f(orow[ss * 68]);
        c = fmaf(f, c - z, z);                        // f*c + (1-f)*z
        hout[(size_t)ss * 512] = f2bf(o * c);
      }
    }
  }
  if (l < 16) c1[b * 512 + hw + l] = c;
}

// ---------------------------------------------------------------------------
// fused2: layer-2 GEMM(K=512) + act + fo-pool carry, one quarter of S.
// Block = (hr 0..7, b 0..127): 64-h slice. Wave wv owns z AND f of its 16-h
// sub-slice: breg 2x16 bf16x8 = 128 VGPR (register-resident via lb(256,2)).
// A-ring: ring-3 16KB bufs via global_load_lds, counted vmcnt(8/4/0), ONE
// barrier per tile; zf double-buffered; per-wave scan (lanes 0-15).
// ---------------------------------------------------------------------------
__global__ __launch_bounds__(256, 2) void fused2(const u16* __restrict__ h1q,
                                                 const u16* __restrict__ w2t,
                                                 const float* __restrict__ b2,
                                                 float* __restrict__ c2,
                                                 const float* __restrict__ ol,
                                                 float* __restrict__ h2l,
                                                 int first, int last) {
  constexpr int T = QS_ / 16;                         // 16
  __shared__ __align__(16) u16 Aring[3][8192];        // [16 ktile][16 rows][64B]
  __shared__ u16 zfb[2][16 * 132];                    // [par][row*132 + h*2]
  const int t = threadIdx.x;
  const int l = t & 63, wv = t >> 6;
  const int lr = l & 15, lg = l >> 4;
  const int bid = blockIdx.x;
  const int hr = bid >> 7, b = bid & 127;
  const int hb = hr * 64;
  const int hw = hb + wv * 16;

  // B fragments (z and f columns of this wave's 16-h slice), K=512
  bf16x8 bz[16], bff[16];
  {
    const u16* wpz = w2t + (size_t)(hw + lr) * 512 + lg * 8;
    const u16* wpf = w2t + (size_t)(512 + hw + lr) * 512 + lg * 8;
#pragma unroll
    for (int kk = 0; kk < 16; kk++) {
      bz[kk]  = *(const bf16x8*)(wpz + kk * 32);
      bff[kk] = *(const bf16x8*)(wpf + kk * 32);
    }
  }
  const float biasz = b2[hw + lr];
  const float biasf = b2[512 + hw + lr];
  float c = 0.f;
  if (l < 16 && !first) c = c2[b * 512 + hw + l];

  // staging offsets: 4 gload_lds per tile per wave; wave covers ktiles
  // {wv, 4+wv, 8+wv, 12+wv}, lane covers (row = l>>2, seg swizzled)
  u32 goff[4];
#pragma unroll
  for (int cc = 0; cc < 4; cc++) {
    int row = l >> 2, pseg = l & 3;
    int lseg = pseg ^ ((row & 3) ^ ((row >> 2) & 3));
    int ktile = cc * 4 + wv;
    goff[cc] = (u32)((b * QS_ + row) * 512 + ktile * 32 + lseg * 8);
  }

#define STG2(rb_, tile) do {                                                   \
    _Pragma("unroll")                                                          \
    for (int cc = 0; cc < 4; cc++)                                             \
      __builtin_amdgcn_global_load_lds(                                        \
        (const __attribute__((address_space(1))) void*)(h1q + goff[cc] + (tile) * 16 * 512), \
        (__attribute__((address_space(3))) void*)(&Aring[rb_][cc * 2048 + wv * 512]), 16, 0, 0); \
  } while (0)

  WAITV0;                                             // drain breg/bias/c2 loads
  STG2(0, 0);
  STG2(1, 1);

  const f32x4 zero4 = {0.f, 0.f, 0.f, 0.f};
  for (int tt = 0; tt < T; ++tt) {
    const int rb = tt % 3;
    if (tt + 2 < T) { STG2((tt + 2) % 3, tt + 2); WAITV8; }
    else if (tt + 1 < T) { WAITV4; }
    else { WAITV0; }
    WAITL; SCHED0; SBAR; SCHED0;                      // ring[rb] staged; zf[par^1] visible

    f32x4 zl = zero4, zh = zero4, fl = zero4, fh = zero4;
    const char* Ab = (const char*)&Aring[rb][0];
#pragma unroll
    for (int kk = 0; kk < 16; kk++) {
      bf16x8 af = *(const bf16x8*)(Ab + kk * 1024 + swz_off(lr, lg));
      if (kk < 8) {
        zl = __builtin_amdgcn_mfma_f32_16x16x32_bf16(af, bz[kk],  zl, 0, 0, 0);
        fl = __builtin_amdgcn_mfma_f32_16x16x32_bf16(af, bff[kk], fl, 0, 0, 0);
      } else {
        zh = __builtin_amdgcn_mfma_f32_16x16x32_bf16(af, bz[kk],  zh, 0, 0, 0);
        fh = __builtin_amdgcn_mfma_f32_16x16x32_bf16(af, bff[kk], fh, 0, 0, 0);
      }
    }
    const int par = tt & 1;
    f32x4 za = zl + zh, fa = fl + fh;
#pragma unroll
    for (int r = 0; r < 4; r++) {
      float zv = tanh_safe(za[r] + biasz);
      float fv = sigm(fa[r] + biasf);
      *(u32*)(&zfb[par][(lg * 4 + r) * 132 + (wv * 16 + lr) * 2]) =
          (u32)f2bf(zv) | ((u32)f2bf(fv) << 16);
    }
    // scan tile tt-1 (zf[par^1]); lanes 0-15 own h = hw + l
    if (tt > 0 && l < 16) {
      const u16* zrow = &zfb[par ^ 1][(wv * 16 + l) * 2];
#pragma unroll
      for (int ss = 0; ss < 16; ss++) {
        u32 v = *(const u32*)(zrow + ss * 132);
        float z = bf2f((u16)v), f = bf2f((u16)(v >> 16));
        c = fmaf(f, c - z, z);
      }
    }
  }
#undef STG2
  WAITL; SCHED0; SBAR;                                // last zf visible
  if (l < 16) {
    const u16* zrow = &zfb[(T - 1) & 1][(wv * 16 + l) * 2];
#pragma unroll
    for (int ss = 0; ss < 16; ss++) {
      u32 v = *(const u32*)(zrow + ss * 132);
      float z = bf2f((u16)v), f = bf2f((u16)(v >> 16));
      c = fmaf(f, c - z, z);
    }
    const int idx = b * 512 + hw + l;
    c2[idx] = c;
    if (last) h2l[idx] = ol[idx] * c;
  }
}

// ---------------------------------------------------------------------------
// o_last_k: o2-gate for the 128 rows at s = S-1 (last quarter, row QS-1).
// ---------------------------------------------------------------------------
__global__ __launch_bounds__(256) void o_last_k(const u16* __restrict__ h1q,
                                                const u16* __restrict__ w2t,
                                                const float* __restrict__ b2,
                                                float* __restrict__ olast) {
  __shared__ float hs[H_];
  const int b = blockIdx.x;
  const u16* hrow = h1q + ((size_t)b * QS_ + QS_ - 1) * H_;
  for (int k = threadIdx.x; k < H_; k += 256) hs[k] = bf2f(hrow[k]);
  __syncthreads();
  for (int n = threadIdx.x; n < H_; n += 256) {
    const u16* wr = w2t + (size_t)(1024 + n) * H_;
    float acc = 0.f;
#pragma unroll 8
    for (int k = 0; k < H_; k++) acc = fmaf(hs[k], bf2f(wr[k]), acc);
    olast[(size_t)b * H_ + n] = sigm(acc + b2[1024 + n]);
  }
}

// ---------------------------------------------------------------------------
// final_fc: out = h2_last @ Wfc + bfc.  (128x512)@(512x64) fp32.
// ---------------------------------------------------------------------------
__global__ __launch_bounds__(256) void final_fc(const float* __restrict__ h2l,
                                                const float* __restrict__ Wfc,
                                                const float* __restrict__ bfc,
                                                float* __restrict__ out) {
  __shared__ float red[4][64];
  const int b = blockIdx.x;
  const int t = threadIdx.x, d = t & 63, q = t >> 6;
  const float* hrow = h2l + (size_t)b * H_;
  float acc = 0.f;
#pragma unroll 4
  for (int h = q * 128; h < (q + 1) * 128; h++)
    acc = fmaf(hrow[h], Wfc[(size_t)h * D_ + d], acc);
  red[q][d] = acc;
  __syncthreads();
  if (q == 0)
    out[(size_t)b * D_ + d] = red[0][d] + red[1][d] + red[2][d] + red[3][d] + bfc[d];
}

// ---------------------------------------------------------------------------
extern "C" void kernel_launch(void* const* d_in, const int* in_sizes, int n_in,
                              void* d_out, int out_size, void* d_ws, size_t ws_size,
                              hipStream_t stream) {
  (void)in_sizes; (void)n_in; (void)out_size; (void)ws_size;
  const float* x   = (const float*)d_in[0];
  const float* W1  = (const float*)d_in[1];
  const float* b1  = (const float*)d_in[2];
  const float* W2  = (const float*)d_in[3];
  const float* b2  = (const float*)d_in[4];
  const float* Wfc = (const float*)d_in[5];
  const float* bfc = (const float*)d_in[6];
  float* out = (float*)d_out;
  char* ws = (char*)d_ws;

  u16*   h1q   = (u16*)(ws);                          // 33,554,432
  u16*   w2t   = (u16*)(ws + 33554432ull);            //  1,572,864
  u16*   w1t   = (u16*)(ws + 35127296ull);            //    196,608
  float* c1    = (float*)(ws + 35323904ull);          //    262,144
  float* c2    = (float*)(ws + 35586048ull);          //    262,144
  float* olast = (float*)(ws + 35848192ull);          //    262,144
  float* h2l   = (float*)(ws + 36110336ull);          //    262,144

  prek<<<216, 256, 0, stream>>>(W1, w1t, W2, w2t);
  constexpr int NQ = S_ / QS_;                        // 4
  for (int q = 0; q < NQ; q++) {
    fused1<<<8 * 128, 256, 0, stream>>>(x, w1t, b1, h1q, c1, q * QS_, q == 0);
    if (q == NQ - 1)
      o_last_k<<<B_, 256, 0, stream>>>(h1q, w2t, b2, olast);
    fused2<<<8 * 128, 256, 0, stream>>>(h1q, w2t, b2, c2, olast, h2l,
                                        q == 0, q == NQ - 1);
  }
  final_fc<<<B_, 256, 0, stream>>>(h2l, Wfc, bfc, out);
}